// Round 9
// baseline (2252.405 us; speedup 1.0000x reference)
//
#include <hip/hip_runtime.h>
#include <cmath>

// Problem constants
#define NX 96
#define NY 96
#define NZ 16
#define XYZ (NX*NY*NZ)      // 147456
#define SX 48
#define SY 48
#define SZ 8
#define ND (SX*SY*SZ)       // 18432
#define CH 64
#define EPS_D 1e-5

// ---------------------------------------------------------------------------
// conv3x3 (64 -> 32), stride 1, SAME padding, no bias. 16 oc per block (r9).
// block (16,4,4) = 256 threads; tile 4x4x16 outputs; grid (24,24,2) = 1152.
// LDS layout [p][lx 6][ly 6][z 48slots], z innermost (conflict-free, r7: 0).
// Register double-buffer (r8): next-round loads issue right after ds_writes,
// latency hides under the (now 1728-cycle) FMA block. 16 oc doubles FMA per
// ds_read and halves barriers + halo refetch per output.
// Epilogue: per-block GroupNorm partial sums (psum/psq [32ch][576]).
// ---------------------------------------------------------------------------
template <int NORM>
__global__ __launch_bounds__(256, 4)
void conv3x3_kernel(const float* __restrict__ in,
                    const float* __restrict__ w,   // (32,64,27)
                    const float* __restrict__ stats,
                    const float* __restrict__ gamma,
                    const float* __restrict__ beta,
                    float* __restrict__ out,
                    float* __restrict__ psum,      // [32][576]
                    float* __restrict__ psq) {
    __shared__ float smraw[2 * 1728 + 1];
    float* sm = smraw + 1;
    const int tz = threadIdx.x;          // 0..15
    const int ty = threadIdx.y;          // 0..3
    const int tx = threadIdx.z;          // 0..3 (= wave id)
    const int x0 = blockIdx.x * 4;
    const int y0 = blockIdx.y * 4;
    const int oc0 = blockIdx.z * 16;
    const int t = tz + 16 * ty + 64 * tx;

    // staging assignment 0: quad qi = t; assignment 1: qi = 256+t (t<32)
    int lds0, gof0, lds1, gof1, p0;
    bool v0, w1, v1;
    {
        int qi = t;
        p0 = qi >= 144 ? 1 : 0;
        int rc = qi - p0 * 144;
        int col = rc >> 2, qz = rc & 3;
        int lx = col / 6, ly = col - lx * 6;
        lds0 = p0 * 1728 + lx * 288 + ly * 48 + qz * 4;
        int ix = x0 + lx - 1, iy = y0 + ly - 1;
        v0 = ((unsigned)ix < NX) && ((unsigned)iy < NY);
        gof0 = (ix * NY + iy) * NZ + qz * 4 + (p0 ? XYZ : 0);
    }
    {
        int rc = 256 + t - 144;          // plane 1 always
        int col = rc >> 2, qz = rc & 3;
        int lx = col / 6, ly = col - lx * 6;
        lds1 = 1728 + lx * 288 + ly * 48 + qz * 4;
        int ix = x0 + lx - 1, iy = y0 + ly - 1;
        w1 = (t < 32);
        v1 = w1 && ((unsigned)ix < NX) && ((unsigned)iy < NY);
        gof1 = (ix * NY + iy) * NZ + qz * 4 + XYZ;
    }

    // prologue: issue loads for round 0 immediately (latency hides under
    // the pad-zeroing below and the first barrier)
    float4 a0 = {0.f, 0.f, 0.f, 0.f}, a1 = {0.f, 0.f, 0.f, 0.f};
    if (v0) a0 = *(const float4*)(in + gof0);
    if (v1) a1 = *(const float4*)(in + gof1);

    // zero pad slots once; never rewritten by staging (which writes z 0..15)
    for (int i = t; i < 72 * 32; i += 256) {
        int c = i >> 5, k = i & 31;
        sm[c * 48 + 16 + k] = 0.f;
    }
    if (t == 0) smraw[0] = 0.f;

    float acc[16];
#pragma unroll
    for (int o = 0; o < 16; ++o) acc[o] = 0.f;

    for (int ic0 = 0; ic0 < 64; ic0 += 2) {
        float s0 = 1.f, h0 = 0.f, s1 = 1.f, h1 = 0.f;
        if (NORM) {   // ic0 even: ic0, ic0+1 share a group (2 ch/group)
            float m = stats[ic0], r = stats[ic0 + 1];   // stats[2g],stats[2g+1]
            s0 = gamma[ic0] * r;     h0 = beta[ic0] - m * s0;
            s1 = gamma[ic0 + 1] * r; h1 = beta[ic0 + 1] - m * s1;
        }
        __syncthreads();   // previous round's LDS reads done before overwrite
        // write current-round registers (NORM applied at write time)
        float4 wa0 = a0, wa1 = a1;
        if (NORM) {
            float sc = p0 ? s1 : s0, sh = p0 ? h1 : h0;
            if (v0) {
                wa0.x = fmaf(a0.x, sc, sh); wa0.y = fmaf(a0.y, sc, sh);
                wa0.z = fmaf(a0.z, sc, sh); wa0.w = fmaf(a0.w, sc, sh);
            }
            if (v1) {
                wa1.x = fmaf(a1.x, s1, h1); wa1.y = fmaf(a1.y, s1, h1);
                wa1.z = fmaf(a1.z, s1, h1); wa1.w = fmaf(a1.w, s1, h1);
            }
        }
        *(float4*)(sm + lds0) = wa0;
        if (w1) *(float4*)(sm + lds1) = wa1;

        // prefetch next round into registers (latency hides under compute)
        float4 b0 = {0.f, 0.f, 0.f, 0.f}, b1 = {0.f, 0.f, 0.f, 0.f};
        if (ic0 + 2 < 64) {
            const float* nbase = in + (size_t)(ic0 + 2) * XYZ;
            if (v0) b0 = *(const float4*)(nbase + gof0);
            if (v1) b1 = *(const float4*)(nbase + gof1);
        }
        __syncthreads();   // LDS writes visible

#pragma unroll
        for (int p = 0; p < 2; ++p) {
            const int rb = p * 1728 + tx * 288 + ty * 48 + tz - 1;
            float val[27];
#pragma unroll
            for (int dx = 0; dx < 3; ++dx)
#pragma unroll
                for (int dy = 0; dy < 3; ++dy)
#pragma unroll
                    for (int dz = 0; dz < 3; ++dz)
                        val[dx * 9 + dy * 3 + dz] = sm[rb + dx * 288 + dy * 48 + dz];
            const float* wp = w + ((size_t)oc0 * 64 + ic0 + p) * 27;
#pragma unroll
            for (int o = 0; o < 16; ++o) {
#pragma unroll
                for (int k = 0; k < 27; ++k)
                    acc[o] = fmaf(val[k], wp[o * 1728 + k], acc[o]);
            }
        }
        a0 = b0; a1 = b1;
    }

    const int gx = x0 + tx, gy = y0 + ty;
    const int vofs = (gx * NY + gy) * NZ + tz;
#pragma unroll
    for (int o = 0; o < 16; ++o)
        out[(size_t)(oc0 + o) * XYZ + vofs] = acc[o];

    // ---- per-block GroupNorm partial sums (16 oc) ----
    float rs[16], rq[16];
#pragma unroll
    for (int o = 0; o < 16; ++o) { rs[o] = acc[o]; rq[o] = acc[o] * acc[o]; }
#pragma unroll
    for (int d = 1; d < 64; d <<= 1) {
#pragma unroll
        for (int o = 0; o < 16; ++o) {
            rs[o] += __shfl_xor(rs[o], d);
            rq[o] += __shfl_xor(rq[o], d);
        }
    }
    __syncthreads();           // all sm reads done; reuse as reduction buffer
    const int lane = tz + 16 * ty;
    if (lane == 0) {
#pragma unroll
        for (int o = 0; o < 16; ++o) {
            sm[tx * 32 + o]      = rs[o];
            sm[tx * 32 + 16 + o] = rq[o];
        }
    }
    __syncthreads();
    if (t < 32) {
        int o = t & 15;
        int base = t & 16;
        float tot = sm[base + o] + sm[32 + base + o] + sm[64 + base + o] + sm[96 + base + o];
        int bflat = blockIdx.y * 24 + blockIdx.x;
        if (t < 16) psum[(size_t)(oc0 + o) * 576 + bflat] = tot;
        else        psq [(size_t)(oc0 + o) * 576 + bflat] = tot;
    }
}

// ---------------------------------------------------------------------------
// stage-2 reduction of GroupNorm partials.
// psum/psq layout [nch][nblocks]; group g = channels [g*cpg,(g+1)*cpg).
// ---------------------------------------------------------------------------
__global__ void gn_stage2_kernel(const float* __restrict__ psum,
                                 const float* __restrict__ psq,
                                 float* __restrict__ stats,
                                 int nblocks, int cpg, float gsize) {
    const int g = blockIdx.x;
    const int n = cpg * nblocks;
    const size_t off = (size_t)g * n;
    double s = 0.0, ss = 0.0;
    for (int i = threadIdx.x; i < n; i += blockDim.x) {
        s  += (double)psum[off + i];
        ss += (double)psq[off + i];
    }
    for (int d = 32; d > 0; d >>= 1) {
        s  += __shfl_down(s, d);
        ss += __shfl_down(ss, d);
    }
    __shared__ double shs[4], shss[4];
    const int lane = threadIdx.x & 63, wid = threadIdx.x >> 6;
    if (lane == 0) { shs[wid] = s; shss[wid] = ss; }
    __syncthreads();
    if (threadIdx.x == 0) {
        double S = 0.0, SS = 0.0;
        for (int i = 0; i < 4; ++i) { S += shs[i]; SS += shss[i]; }
        double m = S / gsize;
        double var = SS / gsize - m * m;
        stats[2 * g]     = (float)m;
        stats[2 * g + 1] = (float)(1.0 / sqrt(var + EPS_D));
    }
}

// ---------------------------------------------------------------------------
// fused GroupNorm stats for q (32 groups), k (192), v (192): 416 blocks.
// All groups are contiguous 2*ND floats. float4 loads.
// ---------------------------------------------------------------------------
__global__ void gn_stats3_kernel(const float* __restrict__ qb,
                                 const float* __restrict__ kb,
                                 const float* __restrict__ vb,
                                 float* __restrict__ stats) {
    const int b = blockIdx.x;
    const float* src;
    float* dst;
    int g;
    if (b < 32)       { src = qb; g = b;       dst = stats + 64;  }
    else if (b < 224) { src = kb; g = b - 32;  dst = stats + 128; }
    else              { src = vb; g = b - 224; dst = stats + 512; }
    const float4* p = (const float4*)(src + (size_t)g * (2 * ND));
    double s = 0.0, ss = 0.0;
    for (int i = threadIdx.x; i < (2 * ND) / 4; i += 256) {
        float4 x = p[i];
        s  += (double)x.x + (double)x.y + (double)x.z + (double)x.w;
        ss += (double)x.x * x.x + (double)x.y * x.y +
              (double)x.z * x.z + (double)x.w * x.w;
    }
    for (int d = 32; d > 0; d >>= 1) {
        s  += __shfl_down(s, d);
        ss += __shfl_down(ss, d);
    }
    __shared__ double shs[4], shss[4];
    const int lane = threadIdx.x & 63, wid = threadIdx.x >> 6;
    if (lane == 0) { shs[wid] = s; shss[wid] = ss; }
    __syncthreads();
    if (threadIdx.x == 0) {
        double S = 0.0, SS = 0.0;
        for (int i = 0; i < 4; ++i) { S += shs[i]; SS += shss[i]; }
        double m = S / (2.0 * ND);
        double var = SS / (2.0 * ND) - m * m;
        dst[2 * g]     = (float)m;
        dst[2 * g + 1] = (float)(1.0 / sqrt(var + EPS_D));
    }
}

// ---------------------------------------------------------------------------
// fused: GroupNorm(32ch, 32 groups) -> ReLU -> 1x1 conv (32 -> NOUT)
// ---------------------------------------------------------------------------
template <int NOUT>
__global__ void head_kernel(const float* __restrict__ h,
                            const float* __restrict__ stats,
                            const float* __restrict__ gamma,
                            const float* __restrict__ beta,
                            const float* __restrict__ w2,   // (NOUT,32)
                            float* __restrict__ out) {
    const int v = blockIdx.x * 256 + threadIdx.x;
    if (v >= XYZ) return;
    float acc[NOUT];
#pragma unroll
    for (int o = 0; o < NOUT; ++o) acc[o] = 0.f;
#pragma unroll
    for (int ic = 0; ic < 32; ++ic) {
        float m = stats[2 * ic], r = stats[2 * ic + 1];
        float val = (h[(size_t)ic * XYZ + v] - m) * r * gamma[ic] + beta[ic];
        val = fmaxf(val, 0.f);
#pragma unroll
        for (int o = 0; o < NOUT; ++o)
            acc[o] = fmaf(val, w2[o * 32 + ic], acc[o]);
    }
#pragma unroll
    for (int o = 0; o < NOUT; ++o) out[(size_t)o * XYZ + v] = acc[o];
}

// ---------------------------------------------------------------------------
// trilinear downsample (exact 2x2x2 average), float4-vectorized: one thread
// per output (ch, a, b) column (8 outputs). Optional GN-affine + sigmoid.
// ---------------------------------------------------------------------------
__global__ void downsample_kernel(const float* __restrict__ in,
                                  float* __restrict__ out, int totalCols,
                                  int applySigmoid,
                                  const float* __restrict__ stats,
                                  const float* __restrict__ gamma,
                                  const float* __restrict__ beta) {
    int idx = blockIdx.x * 256 + threadIdx.x;
    if (idx >= totalCols) return;
    int b  = idx % SY;
    int r  = idx / SY;
    int a  = r % SX;
    int ch = r / SX;
    const float4* r0 = (const float4*)(in + (((size_t)ch * NX + 2 * a) * NY + 2 * b) * NZ);
    const float4* r1 = (const float4*)(in + (((size_t)ch * NX + 2 * a + 1) * NY + 2 * b) * NZ);
    float sc = 1.f, sh = 0.f;
    if (stats) {
        float m = stats[2 * (ch >> 1)], rr = stats[2 * (ch >> 1) + 1];
        sc = rr * gamma[ch];
        sh = beta[ch] - m * sc;
    }
    float o8[8];
#pragma unroll
    for (int q = 0; q < 4; ++q) {
        float4 A = r0[q], B = r0[q + 4], C = r1[q], D = r1[q + 4];
        float e0 = (A.x + A.y + B.x + B.y + C.x + C.y + D.x + D.y) * 0.125f;
        float e1 = (A.z + A.w + B.z + B.w + C.z + C.w + D.z + D.w) * 0.125f;
        if (stats) { e0 = fmaf(e0, sc, sh); e1 = fmaf(e1, sc, sh); }
        if (applySigmoid) {
            e0 = 1.f / (1.f + expf(-e0));
            e1 = 1.f / (1.f + expf(-e1));
        }
        o8[2 * q] = e0; o8[2 * q + 1] = e1;
    }
    float* op = out + (((size_t)ch * SX + a) * SY + b) * SZ;
    *(float4*)op       = make_float4(o8[0], o8[1], o8[2], o8[3]);
    *(float4*)(op + 4) = make_float4(o8[4], o8[5], o8[6], o8[7]);
}

// ---------------------------------------------------------------------------
// fused generate_grids + grid_sample; 8 channels per thread.
// ---------------------------------------------------------------------------
__global__ void gridsample_kernel(const float* __restrict__ xd,
                                  const float* __restrict__ offs,
                                  float* __restrict__ nb) {
    int idx = blockIdx.x * 256 + threadIdx.x;
    if (idx >= 48 * ND) return;
    int vox = idx % ND;
    int t2  = idx / ND;
    int cg  = t2 & 7;
    int n   = t2 >> 3;
    int c2  = vox & 7;
    int b   = (vox >> 3) % SY;
    int a   = vox / (8 * SY);
    float o = offs[n * ND + vox];

    float sx = (float)a, sy = (float)b, sz = (float)c2;
    switch (n) {
        case 0: sx = fminf(fmaxf(sx + o * 47.f, 0.f), 47.f); break;
        case 1: sx = fminf(fmaxf(sx - o * 47.f, 0.f), 47.f); break;
        case 2: sy = fminf(fmaxf(sy + o * 47.f, 0.f), 47.f); break;
        case 3: sy = fminf(fmaxf(sy - o * 47.f, 0.f), 47.f); break;
        case 4: sz = fminf(fmaxf(sz + o * 7.f, 0.f), 7.f); break;
        default: sz = fminf(fmaxf(sz - o * 7.f, 0.f), 7.f); break;
    }
    float u0 = 2.f * sx / 47.f - 1.f;
    float u1 = 2.f * sy / 47.f - 1.f;
    float u2 = 2.f * sz / 7.f - 1.f;
    // torch grid_sample: comp0 -> W axis (=SZ), comp1 -> H (=SY), comp2 -> D (=SX)
    float ix = ((u0 + 1.f) * (float)SZ - 1.f) * 0.5f;
    float iy = ((u1 + 1.f) * (float)SY - 1.f) * 0.5f;
    float iz = ((u2 + 1.f) * (float)SX - 1.f) * 0.5f;
    float x0f = floorf(ix), y0f = floorf(iy), z0f = floorf(iz);
    float wx = ix - x0f, wy = iy - y0f, wz = iz - z0f;
    int x0 = (int)x0f, y0 = (int)y0f, z0 = (int)z0f;

    int   lin[8];
    float wt[8];
#pragma unroll
    for (int t = 0; t < 8; ++t) {
        int dx = t & 1, dy = (t >> 1) & 1, dz = (t >> 2) & 1;
        int xc = x0 + dx, yc = y0 + dy, zc = z0 + dz;
        bool valid = (xc >= 0 && xc < SZ && yc >= 0 && yc < SY && zc >= 0 && zc < SX);
        int xcc = min(max(xc, 0), SZ - 1);
        int ycc = min(max(yc, 0), SY - 1);
        int zcc = min(max(zc, 0), SX - 1);
        lin[t] = (zcc * SY + ycc) * SZ + xcc;
        wt[t] = (dx ? wx : 1.f - wx) * (dy ? wy : 1.f - wy) * (dz ? wz : 1.f - wz)
                * (valid ? 1.f : 0.f);
    }
    float* op = nb + ((size_t)n * CH + cg * 8) * ND + vox;
#pragma unroll
    for (int j = 0; j < 8; ++j) {
        const float* vp = xd + (size_t)(cg * 8 + j) * ND;
        float s = 0.f;
#pragma unroll
        for (int t = 0; t < 8; ++t)
            if (wt[t] != 0.f) s = fmaf(vp[lin[t]], wt[t], s);
        op[(size_t)j * ND] = s;
    }
}

// ---------------------------------------------------------------------------
// 1x1 conv 64->64, 16 output channels per thread; wt transposed (ic,oc)
// ---------------------------------------------------------------------------
__global__ void conv1x1_oc16_kernel(const float* __restrict__ in,
                                    const float* __restrict__ wt,
                                    float* __restrict__ out, int N, int S) {
    int idx = blockIdx.x * 256 + threadIdx.x;
    int total = S * N;
    if (idx >= 4 * total) return;
    int q = idx / total;
    int r = idx - q * total;
    int s = r / N, v = r - s * N;
    const float* ip = in + (size_t)s * 64 * N + v;
    float acc[16];
#pragma unroll
    for (int o = 0; o < 16; ++o) acc[o] = 0.f;
    for (int ic = 0; ic < 64; ++ic) {
        float val = ip[(size_t)ic * N];
        const float* wr = wt + ic * 64 + q * 16;
#pragma unroll
        for (int o = 0; o < 16; ++o)
            acc[o] = fmaf(val, wr[o], acc[o]);
    }
    float* op = out + ((size_t)s * 64 + q * 16) * N + v;
#pragma unroll
    for (int o = 0; o < 16; ++o) op[(size_t)o * N] = acc[o];
}

// ---------------------------------------------------------------------------
// fused 1x1 convs k AND v from one nbb read. 16 oc each per thread.
// ---------------------------------------------------------------------------
__global__ void conv1x1_kv_kernel(const float* __restrict__ in,   // (6,64,ND)
                                  const float* __restrict__ wtk,
                                  const float* __restrict__ wtv,
                                  float* __restrict__ kout,
                                  float* __restrict__ vout) {
    int idx = blockIdx.x * 256 + threadIdx.x;
    if (idx >= 24 * ND) return;
    int v = idx % ND;
    int r = idx / ND;
    int s = r % 6;
    int q = r / 6;
    const float* ip = in + (size_t)s * 64 * ND + v;
    float ak[16], av[16];
#pragma unroll
    for (int o = 0; o < 16; ++o) { ak[o] = 0.f; av[o] = 0.f; }
    for (int ic = 0; ic < 64; ++ic) {
        float x = ip[(size_t)ic * ND];
        const float* wkr = wtk + ic * 64 + q * 16;
        const float* wvr = wtv + ic * 64 + q * 16;
#pragma unroll
        for (int o = 0; o < 16; ++o) {
            ak[o] = fmaf(x, wkr[o], ak[o]);
            av[o] = fmaf(x, wvr[o], av[o]);
        }
    }
    float* kp = kout + ((size_t)s * 64 + q * 16) * ND + v;
    float* vp = vout + ((size_t)s * 64 + q * 16) * ND + v;
#pragma unroll
    for (int o = 0; o < 16; ++o) {
        kp[(size_t)o * ND] = ak[o];
        vp[(size_t)o * ND] = av[o];
    }
}

// transpose all eight 64x64 weight matrices: grid 8
__global__ void transpose_w4_kernel(const float* __restrict__ q,
                                    const float* __restrict__ k,
                                    const float* __restrict__ v,
                                    const float* __restrict__ o,
                                    float* __restrict__ wt) {
    int m = blockIdx.x;            // 0..7: family = m>>1 (Q,K,V,O), layer = m&1
    const float* src = (m < 2 ? q : m < 4 ? k : m < 6 ? v : o) + (m & 1) * 4096;
    float* dst = wt + (size_t)(m >> 1) * 8192 + (m & 1) * 4096;
    for (int i = threadIdx.x; i < 4096; i += 256) {
        int oc = i >> 6, ic = i & 63;
        dst[ic * 64 + oc] = src[oc * 64 + ic];
    }
}

// ---------------------------------------------------------------------------
// attention scores: one thread per (direction, voxel)
// ---------------------------------------------------------------------------
__global__ void attn_score_kernel(const float* __restrict__ qraw,
                                  const float* __restrict__ kraw,
                                  const float* __restrict__ qstats,
                                  const float* __restrict__ kstats,
                                  const float* __restrict__ gq, const float* __restrict__ bq,
                                  const float* __restrict__ gk, const float* __restrict__ bk,
                                  float* __restrict__ sc) {
    int idx = blockIdx.x * 256 + threadIdx.x;
    if (idx >= 6 * ND) return;
    int v = idx % ND;
    int n = idx / ND;
    const float* kp = kraw + (size_t)n * 64 * ND + v;
    const float* ks = kstats + n * 64;
    float s = 0.f;
#pragma unroll
    for (int c = 0; c < 64; ++c) {
        float qm = qstats[2 * (c >> 1)], qr = qstats[2 * (c >> 1) + 1];
        float qn = (qraw[(size_t)c * ND + v] - qm) * qr * gq[c] + bq[c];
        float km = ks[2 * (c >> 1)], kr = ks[2 * (c >> 1) + 1];
        float kn = (kp[(size_t)c * ND] - km) * kr * gk[c] + bk[c];
        s = fmaf(kn, qn, s);
    }
    sc[idx] = s * 0.125f;
}

// ---------------------------------------------------------------------------
// softmax over 6 + weighted aggregation of normalized v; 8 ch per thread
// ---------------------------------------------------------------------------
__global__ void attn_agg_kernel(const float* __restrict__ vraw,
                                const float* __restrict__ sc,
                                const float* __restrict__ vstats,
                                const float* __restrict__ gv, const float* __restrict__ bv,
                                float* __restrict__ agg) {
    int idx = blockIdx.x * 256 + threadIdx.x;
    if (idx >= 8 * ND) return;
    int v  = idx % ND;
    int cg = idx / ND;
    float scv[6];
#pragma unroll
    for (int n = 0; n < 6; ++n) scv[n] = sc[n * ND + v];
    float mx = scv[0];
#pragma unroll
    for (int n = 1; n < 6; ++n) mx = fmaxf(mx, scv[n]);
    float w[6], den = 0.f;
#pragma unroll
    for (int n = 0; n < 6; ++n) { w[n] = expf(scv[n] - mx); den += w[n]; }
    float inv = 1.f / den;
#pragma unroll
    for (int n = 0; n < 6; ++n) w[n] *= inv;
#pragma unroll
    for (int j = 0; j < 8; ++j) {
        int c = cg * 8 + j;
        float s = 0.f;
#pragma unroll
        for (int n = 0; n < 6; ++n) {
            const float* vs = vstats + n * 64;
            float m = vs[2 * (c >> 1)], r = vs[2 * (c >> 1) + 1];
            float vn = (vraw[((size_t)n * 64 + c) * ND + v] - m) * r * gv[c] + bv[c];
            s = fmaf(w[n], vn, s);
        }
        agg[(size_t)c * ND + v] = s;
    }
}

// ---------------------------------------------------------------------------
// fused: trilinear upsample + residual (lazy GN) + 1x1 conv Wo + GN partials.
// Block = 64 voxels x 4 oc-quarters. xv staged in LDS [64ch][65].
// ---------------------------------------------------------------------------
__global__ __launch_bounds__(256, 4)
void fused_out_kernel(const float* __restrict__ agg,
                      const float* __restrict__ xin,
                      const float* __restrict__ wt,   // (ic,oc)
                      float* __restrict__ Aout,
                      float* __restrict__ psum,       // [64][2304]
                      float* __restrict__ psq,
                      const float* __restrict__ pst,
                      const float* __restrict__ pg,
                      const float* __restrict__ pb) {
    __shared__ float xv[64 * 65];
    const int t  = threadIdx.x;
    const int vx = t & 63;
    const int q  = t >> 6;
    const int v  = blockIdx.x * 64 + vx;
    const int z  = v & 15;
    const int y  = (v >> 4) % NY;
    const int x  = v / (16 * NY);

    float cx = fminf(fmaxf(0.5f * x - 0.25f, 0.f), 47.f);
    float cy = fminf(fmaxf(0.5f * y - 0.25f, 0.f), 47.f);
    float cz = fminf(fmaxf(0.5f * z - 0.25f, 0.f), 7.f);
    int x0 = (int)floorf(cx); int x1 = min(x0 + 1, 47); float fx = cx - x0;
    int y0 = (int)floorf(cy); int y1 = min(y0 + 1, 47); float fy = cy - y0;
    int z0 = (int)floorf(cz); int z1 = min(z0 + 1, 7);  float fz = cz - z0;

    int   lin[8];
    float w8[8];
    lin[0] = (x0 * SY + y0) * SZ + z0;  w8[0] = (1.f - fx) * (1.f - fy) * (1.f - fz);
    lin[1] = (x0 * SY + y0) * SZ + z1;  w8[1] = (1.f - fx) * (1.f - fy) * fz;
    lin[2] = (x0 * SY + y1) * SZ + z0;  w8[2] = (1.f - fx) * fy * (1.f - fz);
    lin[3] = (x0 * SY + y1) * SZ + z1;  w8[3] = (1.f - fx) * fy * fz;
    lin[4] = (x1 * SY + y0) * SZ + z0;  w8[4] = fx * (1.f - fy) * (1.f - fz);
    lin[5] = (x1 * SY + y0) * SZ + z1;  w8[5] = fx * (1.f - fy) * fz;
    lin[6] = (x1 * SY + y1) * SZ + z0;  w8[6] = fx * fy * (1.f - fz);
    lin[7] = (x1 * SY + y1) * SZ + z1;  w8[7] = fx * fy * fz;

#pragma unroll
    for (int j = 0; j < 16; ++j) {
        int c = q * 16 + j;
        const float* ap = agg + (size_t)c * ND;
        float s = 0.f;
#pragma unroll
        for (int k = 0; k < 8; ++k) s = fmaf(ap[lin[k]], w8[k], s);
        float xr = xin[(size_t)c * XYZ + v];
        if (pst) {
            float m = pst[2 * (c >> 1)], rr = pst[2 * (c >> 1) + 1];
            xr = (xr - m) * rr * pg[c] + pb[c];
        }
        xv[c * 65 + vx] = s + xr;
    }
    __syncthreads();

    float acc[16];
#pragma unroll
    for (int o = 0; o < 16; ++o) acc[o] = 0.f;
    for (int ic = 0; ic < 64; ++ic) {
        float val = xv[ic * 65 + vx];
        const float* wr = wt + ic * 64 + q * 16;
#pragma unroll
        for (int o = 0; o < 16; ++o)
            acc[o] = fmaf(val, wr[o], acc[o]);
    }
#pragma unroll
    for (int o = 0; o < 16; ++o)
        Aout[(size_t)(q * 16 + o) * XYZ + v] = acc[o];

    float rs[16], rq[16];
#pragma unroll
    for (int o = 0; o < 16; ++o) { rs[o] = acc[o]; rq[o] = acc[o] * acc[o]; }
#pragma unroll
    for (int d = 1; d < 64; d <<= 1) {
#pragma unroll
        for (int o = 0; o < 16; ++o) {
            rs[o] += __shfl_xor(rs[o], d);
            rq[o] += __shfl_xor(rq[o], d);
        }
    }
    if (vx == 0) {
#pragma unroll
        for (int o = 0; o < 16; ++o) {
            psum[(size_t)(q * 16 + o) * 2304 + blockIdx.x] = rs[o];
            psq [(size_t)(q * 16 + o) * 2304 + blockIdx.x] = rq[o];
        }
    }
}

// ---------------------------------------------------------------------------
extern "C" void kernel_launch(void* const* d_in, const int* in_sizes, int n_in,
                              void* d_out, int out_size, void* d_ws, size_t ws_size,
                              hipStream_t stream) {
    (void)in_sizes; (void)n_in; (void)out_size; (void)ws_size;
    const float* cls_feat  = (const float*)d_in[0];
    const float* box_feat  = (const float*)d_in[1];
    const float* bbox_W1   = (const float*)d_in[2];
    const float* bbox_gn_g = (const float*)d_in[3];
    const float* bbox_gn_b = (const float*)d_in[4];
    const float* bbox_W2   = (const float*)d_in[5];
    const float* cls_W1    = (const float*)d_in[6];
    const float* cls_gn_g  = (const float*)d_in[7];
    const float* cls_gn_b  = (const float*)d_in[8];
    const float* cls_W2    = (const float*)d_in[9];
    const float* rWq       = (const float*)d_in[10];
    const float* rWk       = (const float*)d_in[11];
    const float* rWv       = (const float*)d_in[12];
    const float* rWo       = (const float*)d_in[13];
    const float* r_gn_g    = (const float*)d_in[14];  // (2,4,64)
    const float* r_gn_b    = (const float*)d_in[15];

    float* out_cls  = (float*)d_out;          // (18,96,96,16)
    float* out_bbox = out_cls + 18 * XYZ;     // (6,96,96,16)

    float* ws    = (float*)d_ws;
    float* A     = ws;                        // 64*XYZ : evolving x (raw, pre-GN)
    float* Bf    = A + (size_t)64 * XYZ;      // 64*XYZ : scratch (scores + partials)
    float* xdb   = Bf + (size_t)64 * XYZ;     // 64*ND
    float* qb    = xdb + (size_t)64 * ND;     // 64*ND
    float* aggb  = qb + (size_t)64 * ND;      // 64*ND
    float* offs  = aggb + (size_t)64 * ND;    // 6*ND
    float* stats = offs + (size_t)6 * ND;     // 1024
    float* wts   = stats + 1024;              // 8*4096
    float* nbb   = wts + 8 * 4096;            // 6*64*ND
    float* krb   = nbb + (size_t)6 * 64 * ND; // 6*64*ND
    float* vrb   = krb + (size_t)6 * 64 * ND; // 6*64*ND
    float* hbuf  = vrb;                       // conv3x3 output region (32*XYZ)
    float* scb   = Bf;                        // 6*ND score scratch
    float* psum  = Bf + 200000;               // partial sums (up to 64*2304)
    float* psq   = psum + (size_t)64 * 2304;

    transpose_w4_kernel<<<8, 256, 0, stream>>>(rWq, rWk, rWv, rWo, wts);

    dim3 cgrid(24, 24, 2), cblk(16, 4, 4);

    // ---- bbox branch ----
    conv3x3_kernel<0><<<cgrid, cblk, 0, stream>>>(box_feat, bbox_W1,
                                                  nullptr, nullptr, nullptr,
                                                  hbuf, psum, psq);
    gn_stage2_kernel<<<32, 256, 0, stream>>>(psum, psq, stats, 576, 1, (float)XYZ);
    head_kernel<6><<<(XYZ + 255) / 256, 256, 0, stream>>>(hbuf, stats, bbox_gn_g,
                                                          bbox_gn_b, bbox_W2, out_bbox);
    downsample_kernel<<<(6 * SX * SY + 255) / 256, 256, 0, stream>>>(
        out_bbox, offs, 6 * SX * SY, 1, nullptr, nullptr, nullptr);

    // ---- refine stack (2 layers); x kept RAW with deferred out-GN ----
    const float* xcur = cls_feat;
    for (int l = 0; l < 2; ++l) {
        const float* gq = r_gn_g + (l * 4 + 0) * 64; const float* bq = r_gn_b + (l * 4 + 0) * 64;
        const float* gk = r_gn_g + (l * 4 + 1) * 64; const float* bk = r_gn_b + (l * 4 + 1) * 64;
        const float* gv = r_gn_g + (l * 4 + 2) * 64; const float* bv = r_gn_b + (l * 4 + 2) * 64;
        const float* pst = l ? stats + 896 : nullptr;   // layer0 out-GN stats
        const float* pg  = r_gn_g + 3 * 64;
        const float* pb  = r_gn_b + 3 * 64;

        downsample_kernel<<<(64 * SX * SY + 255) / 256, 256, 0, stream>>>(
            xcur, xdb, 64 * SX * SY, 0, pst, pg, pb);
        gridsample_kernel<<<(48 * ND + 255) / 256, 256, 0, stream>>>(xdb, offs, nbb);
        conv1x1_oc16_kernel<<<(4 * ND + 255) / 256, 256, 0, stream>>>(
            xdb, wts + l * 4096, qb, ND, 1);
        conv1x1_kv_kernel<<<(24 * ND + 255) / 256, 256, 0, stream>>>(
            nbb, wts + 8192 + l * 4096, wts + 16384 + l * 4096, krb, vrb);
        gn_stats3_kernel<<<416, 256, 0, stream>>>(qb, krb, vrb, stats);
        attn_score_kernel<<<(6 * ND + 255) / 256, 256, 0, stream>>>(
            qb, krb, stats + 64, stats + 128, gq, bq, gk, bk, scb);
        attn_agg_kernel<<<(8 * ND + 255) / 256, 256, 0, stream>>>(
            vrb, scb, stats + 512, gv, bv, aggb);
        fused_out_kernel<<<XYZ / 64, 256, 0, stream>>>(
            aggb, xcur, wts + 24576 + l * 4096, A, psum, psq, pst, pg, pb);
        gn_stage2_kernel<<<32, 256, 0, stream>>>(
            psum, psq, stats + 896 + l * 64, 2304, 2, (float)(2 * XYZ));
        xcur = A;
    }

    // ---- cls branch (GN of layer-1 output fused into conv staging) ----
    conv3x3_kernel<1><<<cgrid, cblk, 0, stream>>>(A, cls_W1, stats + 960,
                                                  r_gn_g + 7 * 64, r_gn_b + 7 * 64,
                                                  hbuf, psum, psq);
    gn_stage2_kernel<<<32, 256, 0, stream>>>(psum, psq, stats, 576, 1, (float)XYZ);
    head_kernel<18><<<(XYZ + 255) / 256, 256, 0, stream>>>(hbuf, stats, cls_gn_g,
                                                           cls_gn_b, cls_W2, out_cls);
}

// Round 10
// 1618.172 us; speedup vs baseline: 1.3919x; 1.3919x over previous
//
#include <hip/hip_runtime.h>
#include <cmath>

// Problem constants
#define NX 96
#define NY 96
#define NZ 16
#define XYZ (NX*NY*NZ)      // 147456
#define SX 48
#define SY 48
#define SZ 8
#define ND (SX*SY*SZ)       // 18432
#define CH 64
#define EPS_D 1e-5

// DPP row shifts within 16-lane rows; bound_ctrl=true -> 0-fill at row edge,
// which matches the conv's z=-1 / z=16 zero padding exactly.
__device__ __forceinline__ float dpp_shr1(float v) {   // lane n <- lane n-1
    return __int_as_float(__builtin_amdgcn_update_dpp(
        0, __float_as_int(v), 0x111, 0xF, 0xF, true));
}
__device__ __forceinline__ float dpp_shl1(float v) {   // lane n <- lane n+1
    return __int_as_float(__builtin_amdgcn_update_dpp(
        0, __float_as_int(v), 0x101, 0xF, 0xF, true));
}

// ---------------------------------------------------------------------------
// conv3x3 (64 -> 32), stride 1, SAME padding, no bias. 8 oc per block.
// block (16,4,4) = 256 threads; tile 4x4x16 outputs; grid (24,24,4) = 2304
// (r8-proven: >= 9 blocks/CU is mandatory for this barrier-serialized loop).
// r10 change: z-taps via DPP lane shifts -> 9 ds_read_b32 + 18 DPP per plane
// instead of 27 ds_read_b32. LDS shrinks to [2][6][6][16] = 4.6 KB (no pads).
//   read addr = p*576 + (tx+dx)*96 + (ty+dy)*16 + tz
//   bank = (16*(ty+dy) + tz) % 32 = (lane + 16*dy) % 32 -> conflict-free.
// Register double-buffer (r8): next-round loads issue right after ds_writes.
// Epilogue: per-block GroupNorm partial sums (psum/psq [32ch][576]).
// ---------------------------------------------------------------------------
template <int NORM>
__global__ __launch_bounds__(256, 8)
void conv3x3_kernel(const float* __restrict__ in,
                    const float* __restrict__ w,   // (32,64,27)
                    const float* __restrict__ stats,
                    const float* __restrict__ gamma,
                    const float* __restrict__ beta,
                    float* __restrict__ out,
                    float* __restrict__ psum,      // [32][576]
                    float* __restrict__ psq) {
    __shared__ float sm[2 * 576];
    const int tz = threadIdx.x;          // 0..15 (= lane & 15)
    const int ty = threadIdx.y;          // 0..3
    const int tx = threadIdx.z;          // 0..3 (= wave id)
    const int x0 = blockIdx.x * 4;
    const int y0 = blockIdx.y * 4;
    const int oc0 = blockIdx.z * 8;
    const int t = tz + 16 * ty + 64 * tx;

    // staging: 288 float4 quads (2 planes x 144 each).
    // assignment 0: qi = t (0..255); assignment 1: qi = 256+t (t<32).
    int lds0, gof0, lds1, gof1, p0;
    bool v0, w1, v1;
    {
        int qi = t;
        p0 = qi >= 144 ? 1 : 0;
        int rc = qi - p0 * 144;          // 0..143
        int col = rc >> 2, qz = rc & 3;
        int lx = col / 6, ly = col - lx * 6;
        lds0 = p0 * 576 + rc * 4;
        int ix = x0 + lx - 1, iy = y0 + ly - 1;
        v0 = ((unsigned)ix < NX) && ((unsigned)iy < NY);
        gof0 = (ix * NY + iy) * NZ + qz * 4 + (p0 ? XYZ : 0);
    }
    {
        int rc = 112 + t;                // plane 1, quads 112..143
        int col = rc >> 2, qz = rc & 3;
        int lx = col / 6, ly = col - lx * 6;
        lds1 = 576 + rc * 4;
        int ix = x0 + lx - 1, iy = y0 + ly - 1;
        w1 = (t < 32);
        v1 = w1 && ((unsigned)ix < NX) && ((unsigned)iy < NY);
        gof1 = (ix * NY + iy) * NZ + qz * 4 + XYZ;
    }

    // prologue: issue loads for round 0 immediately
    float4 a0 = {0.f, 0.f, 0.f, 0.f}, a1 = {0.f, 0.f, 0.f, 0.f};
    if (v0) a0 = *(const float4*)(in + gof0);
    if (v1) a1 = *(const float4*)(in + gof1);

    float acc[8];
#pragma unroll
    for (int o = 0; o < 8; ++o) acc[o] = 0.f;

    for (int ic0 = 0; ic0 < 64; ic0 += 2) {
        float s0 = 1.f, h0 = 0.f, s1 = 1.f, h1 = 0.f;
        if (NORM) {   // ic0 even: ic0, ic0+1 share a group (2 ch/group)
            float m = stats[ic0], r = stats[ic0 + 1];   // stats[2g],stats[2g+1]
            s0 = gamma[ic0] * r;     h0 = beta[ic0] - m * s0;
            s1 = gamma[ic0 + 1] * r; h1 = beta[ic0 + 1] - m * s1;
        }
        __syncthreads();   // previous round's LDS reads done before overwrite
        // write current-round registers (NORM applied at write time; OOB stays 0)
        float4 wa0 = a0, wa1 = a1;
        if (NORM) {
            float sc = p0 ? s1 : s0, sh = p0 ? h1 : h0;
            if (v0) {
                wa0.x = fmaf(a0.x, sc, sh); wa0.y = fmaf(a0.y, sc, sh);
                wa0.z = fmaf(a0.z, sc, sh); wa0.w = fmaf(a0.w, sc, sh);
            }
            if (v1) {
                wa1.x = fmaf(a1.x, s1, h1); wa1.y = fmaf(a1.y, s1, h1);
                wa1.z = fmaf(a1.z, s1, h1); wa1.w = fmaf(a1.w, s1, h1);
            }
        }
        *(float4*)(sm + lds0) = wa0;
        if (w1) *(float4*)(sm + lds1) = wa1;

        // prefetch next round into registers (latency hides under compute)
        float4 b0 = {0.f, 0.f, 0.f, 0.f}, b1 = {0.f, 0.f, 0.f, 0.f};
        if (ic0 + 2 < 64) {
            const float* nbase = in + (size_t)(ic0 + 2) * XYZ;
            if (v0) b0 = *(const float4*)(nbase + gof0);
            if (v1) b1 = *(const float4*)(nbase + gof1);
        }
        __syncthreads();   // LDS writes visible

#pragma unroll
        for (int p = 0; p < 2; ++p) {
            const int rb = p * 576 + tx * 96 + ty * 16 + tz;
            const float* wp = w + ((size_t)oc0 * 64 + ic0 + p) * 27;
#pragma unroll
            for (int dx = 0; dx < 3; ++dx) {
#pragma unroll
                for (int dy = 0; dy < 3; ++dy) {
                    float v  = sm[rb + dx * 96 + dy * 16];
                    float vm = dpp_shr1(v);   // in[z-1] (0 at z=0 edge = pad)
                    float vp = dpp_shl1(v);   // in[z+1] (0 at z=15 edge = pad)
                    const int kb = dx * 9 + dy * 3;
#pragma unroll
                    for (int o = 0; o < 8; ++o) {
                        acc[o] = fmaf(vm, wp[o * 1728 + kb],     acc[o]);
                        acc[o] = fmaf(v,  wp[o * 1728 + kb + 1], acc[o]);
                        acc[o] = fmaf(vp, wp[o * 1728 + kb + 2], acc[o]);
                    }
                }
            }
        }
        a0 = b0; a1 = b1;
    }

    const int gx = x0 + tx, gy = y0 + ty;
    const int vofs = (gx * NY + gy) * NZ + tz;
#pragma unroll
    for (int o = 0; o < 8; ++o)
        out[(size_t)(oc0 + o) * XYZ + vofs] = acc[o];

    // ---- per-block GroupNorm partial sums ----
    float rs[8], rq[8];
#pragma unroll
    for (int o = 0; o < 8; ++o) { rs[o] = acc[o]; rq[o] = acc[o] * acc[o]; }
#pragma unroll
    for (int d = 1; d < 64; d <<= 1) {
#pragma unroll
        for (int o = 0; o < 8; ++o) {
            rs[o] += __shfl_xor(rs[o], d);
            rq[o] += __shfl_xor(rq[o], d);
        }
    }
    __syncthreads();           // all sm reads done; reuse as reduction buffer
    const int lane = tz + 16 * ty;
    if (lane == 0) {
#pragma unroll
        for (int o = 0; o < 8; ++o) {
            sm[tx * 16 + o]     = rs[o];
            sm[tx * 16 + 8 + o] = rq[o];
        }
    }
    __syncthreads();
    if (t < 16) {
        int o = t & 7;
        int base = (t & 8);
        float tot = sm[base + o] + sm[16 + base + o] + sm[32 + base + o] + sm[48 + base + o];
        int bflat = blockIdx.y * 24 + blockIdx.x;
        if (t < 8) psum[(size_t)(oc0 + o) * 576 + bflat] = tot;
        else       psq [(size_t)(oc0 + o) * 576 + bflat] = tot;
    }
}

// ---------------------------------------------------------------------------
// stage-2 reduction of GroupNorm partials.
// psum/psq layout [nch][nblocks]; group g = channels [g*cpg,(g+1)*cpg).
// ---------------------------------------------------------------------------
__global__ void gn_stage2_kernel(const float* __restrict__ psum,
                                 const float* __restrict__ psq,
                                 float* __restrict__ stats,
                                 int nblocks, int cpg, float gsize) {
    const int g = blockIdx.x;
    const int n = cpg * nblocks;
    const size_t off = (size_t)g * n;
    double s = 0.0, ss = 0.0;
    for (int i = threadIdx.x; i < n; i += blockDim.x) {
        s  += (double)psum[off + i];
        ss += (double)psq[off + i];
    }
    for (int d = 32; d > 0; d >>= 1) {
        s  += __shfl_down(s, d);
        ss += __shfl_down(ss, d);
    }
    __shared__ double shs[4], shss[4];
    const int lane = threadIdx.x & 63, wid = threadIdx.x >> 6;
    if (lane == 0) { shs[wid] = s; shss[wid] = ss; }
    __syncthreads();
    if (threadIdx.x == 0) {
        double S = 0.0, SS = 0.0;
        for (int i = 0; i < 4; ++i) { S += shs[i]; SS += shss[i]; }
        double m = S / gsize;
        double var = SS / gsize - m * m;
        stats[2 * g]     = (float)m;
        stats[2 * g + 1] = (float)(1.0 / sqrt(var + EPS_D));
    }
}

// ---------------------------------------------------------------------------
// fused GroupNorm stats for q (32 groups), k (192), v (192): 416 blocks.
// All groups are contiguous 2*ND floats. float4 loads.
// ---------------------------------------------------------------------------
__global__ void gn_stats3_kernel(const float* __restrict__ qb,
                                 const float* __restrict__ kb,
                                 const float* __restrict__ vb,
                                 float* __restrict__ stats) {
    const int b = blockIdx.x;
    const float* src;
    float* dst;
    int g;
    if (b < 32)       { src = qb; g = b;       dst = stats + 64;  }
    else if (b < 224) { src = kb; g = b - 32;  dst = stats + 128; }
    else              { src = vb; g = b - 224; dst = stats + 512; }
    const float4* p = (const float4*)(src + (size_t)g * (2 * ND));
    double s = 0.0, ss = 0.0;
    for (int i = threadIdx.x; i < (2 * ND) / 4; i += 256) {
        float4 x = p[i];
        s  += (double)x.x + (double)x.y + (double)x.z + (double)x.w;
        ss += (double)x.x * x.x + (double)x.y * x.y +
              (double)x.z * x.z + (double)x.w * x.w;
    }
    for (int d = 32; d > 0; d >>= 1) {
        s  += __shfl_down(s, d);
        ss += __shfl_down(ss, d);
    }
    __shared__ double shs[4], shss[4];
    const int lane = threadIdx.x & 63, wid = threadIdx.x >> 6;
    if (lane == 0) { shs[wid] = s; shss[wid] = ss; }
    __syncthreads();
    if (threadIdx.x == 0) {
        double S = 0.0, SS = 0.0;
        for (int i = 0; i < 4; ++i) { S += shs[i]; SS += shss[i]; }
        double m = S / (2.0 * ND);
        double var = SS / (2.0 * ND) - m * m;
        dst[2 * g]     = (float)m;
        dst[2 * g + 1] = (float)(1.0 / sqrt(var + EPS_D));
    }
}

// ---------------------------------------------------------------------------
// fused: GroupNorm(32ch, 32 groups) -> ReLU -> 1x1 conv (32 -> NOUT)
// ---------------------------------------------------------------------------
template <int NOUT>
__global__ void head_kernel(const float* __restrict__ h,
                            const float* __restrict__ stats,
                            const float* __restrict__ gamma,
                            const float* __restrict__ beta,
                            const float* __restrict__ w2,   // (NOUT,32)
                            float* __restrict__ out) {
    const int v = blockIdx.x * 256 + threadIdx.x;
    if (v >= XYZ) return;
    float acc[NOUT];
#pragma unroll
    for (int o = 0; o < NOUT; ++o) acc[o] = 0.f;
#pragma unroll
    for (int ic = 0; ic < 32; ++ic) {
        float m = stats[2 * ic], r = stats[2 * ic + 1];
        float val = (h[(size_t)ic * XYZ + v] - m) * r * gamma[ic] + beta[ic];
        val = fmaxf(val, 0.f);
#pragma unroll
        for (int o = 0; o < NOUT; ++o)
            acc[o] = fmaf(val, w2[o * 32 + ic], acc[o]);
    }
#pragma unroll
    for (int o = 0; o < NOUT; ++o) out[(size_t)o * XYZ + v] = acc[o];
}

// ---------------------------------------------------------------------------
// trilinear downsample (exact 2x2x2 average), float4-vectorized: one thread
// per output (ch, a, b) column (8 outputs). Optional GN-affine + sigmoid.
// ---------------------------------------------------------------------------
__global__ void downsample_kernel(const float* __restrict__ in,
                                  float* __restrict__ out, int totalCols,
                                  int applySigmoid,
                                  const float* __restrict__ stats,
                                  const float* __restrict__ gamma,
                                  const float* __restrict__ beta) {
    int idx = blockIdx.x * 256 + threadIdx.x;
    if (idx >= totalCols) return;
    int b  = idx % SY;
    int r  = idx / SY;
    int a  = r % SX;
    int ch = r / SX;
    const float4* r0 = (const float4*)(in + (((size_t)ch * NX + 2 * a) * NY + 2 * b) * NZ);
    const float4* r1 = (const float4*)(in + (((size_t)ch * NX + 2 * a + 1) * NY + 2 * b) * NZ);
    float sc = 1.f, sh = 0.f;
    if (stats) {
        float m = stats[2 * (ch >> 1)], rr = stats[2 * (ch >> 1) + 1];
        sc = rr * gamma[ch];
        sh = beta[ch] - m * sc;
    }
    float o8[8];
#pragma unroll
    for (int q = 0; q < 4; ++q) {
        float4 A = r0[q], B = r0[q + 4], C = r1[q], D = r1[q + 4];
        float e0 = (A.x + A.y + B.x + B.y + C.x + C.y + D.x + D.y) * 0.125f;
        float e1 = (A.z + A.w + B.z + B.w + C.z + C.w + D.z + D.w) * 0.125f;
        if (stats) { e0 = fmaf(e0, sc, sh); e1 = fmaf(e1, sc, sh); }
        if (applySigmoid) {
            e0 = 1.f / (1.f + expf(-e0));
            e1 = 1.f / (1.f + expf(-e1));
        }
        o8[2 * q] = e0; o8[2 * q + 1] = e1;
    }
    float* op = out + (((size_t)ch * SX + a) * SY + b) * SZ;
    *(float4*)op       = make_float4(o8[0], o8[1], o8[2], o8[3]);
    *(float4*)(op + 4) = make_float4(o8[4], o8[5], o8[6], o8[7]);
}

// ---------------------------------------------------------------------------
// fused generate_grids + grid_sample; 8 channels per thread.
// ---------------------------------------------------------------------------
__global__ void gridsample_kernel(const float* __restrict__ xd,
                                  const float* __restrict__ offs,
                                  float* __restrict__ nb) {
    int idx = blockIdx.x * 256 + threadIdx.x;
    if (idx >= 48 * ND) return;
    int vox = idx % ND;
    int t2  = idx / ND;
    int cg  = t2 & 7;
    int n   = t2 >> 3;
    int c2  = vox & 7;
    int b   = (vox >> 3) % SY;
    int a   = vox / (8 * SY);
    float o = offs[n * ND + vox];

    float sx = (float)a, sy = (float)b, sz = (float)c2;
    switch (n) {
        case 0: sx = fminf(fmaxf(sx + o * 47.f, 0.f), 47.f); break;
        case 1: sx = fminf(fmaxf(sx - o * 47.f, 0.f), 47.f); break;
        case 2: sy = fminf(fmaxf(sy + o * 47.f, 0.f), 47.f); break;
        case 3: sy = fminf(fmaxf(sy - o * 47.f, 0.f), 47.f); break;
        case 4: sz = fminf(fmaxf(sz + o * 7.f, 0.f), 7.f); break;
        default: sz = fminf(fmaxf(sz - o * 7.f, 0.f), 7.f); break;
    }
    float u0 = 2.f * sx / 47.f - 1.f;
    float u1 = 2.f * sy / 47.f - 1.f;
    float u2 = 2.f * sz / 7.f - 1.f;
    // torch grid_sample: comp0 -> W axis (=SZ), comp1 -> H (=SY), comp2 -> D (=SX)
    float ix = ((u0 + 1.f) * (float)SZ - 1.f) * 0.5f;
    float iy = ((u1 + 1.f) * (float)SY - 1.f) * 0.5f;
    float iz = ((u2 + 1.f) * (float)SX - 1.f) * 0.5f;
    float x0f = floorf(ix), y0f = floorf(iy), z0f = floorf(iz);
    float wx = ix - x0f, wy = iy - y0f, wz = iz - z0f;
    int x0 = (int)x0f, y0 = (int)y0f, z0 = (int)z0f;

    int   lin[8];
    float wt[8];
#pragma unroll
    for (int t = 0; t < 8; ++t) {
        int dx = t & 1, dy = (t >> 1) & 1, dz = (t >> 2) & 1;
        int xc = x0 + dx, yc = y0 + dy, zc = z0 + dz;
        bool valid = (xc >= 0 && xc < SZ && yc >= 0 && yc < SY && zc >= 0 && zc < SX);
        int xcc = min(max(xc, 0), SZ - 1);
        int ycc = min(max(yc, 0), SY - 1);
        int zcc = min(max(zc, 0), SX - 1);
        lin[t] = (zcc * SY + ycc) * SZ + xcc;
        wt[t] = (dx ? wx : 1.f - wx) * (dy ? wy : 1.f - wy) * (dz ? wz : 1.f - wz)
                * (valid ? 1.f : 0.f);
    }
    float* op = nb + ((size_t)n * CH + cg * 8) * ND + vox;
#pragma unroll
    for (int j = 0; j < 8; ++j) {
        const float* vp = xd + (size_t)(cg * 8 + j) * ND;
        float s = 0.f;
#pragma unroll
        for (int t = 0; t < 8; ++t)
            if (wt[t] != 0.f) s = fmaf(vp[lin[t]], wt[t], s);
        op[(size_t)j * ND] = s;
    }
}

// ---------------------------------------------------------------------------
// 1x1 conv 64->64, 16 output channels per thread; wt transposed (ic,oc)
// ---------------------------------------------------------------------------
__global__ void conv1x1_oc16_kernel(const float* __restrict__ in,
                                    const float* __restrict__ wt,
                                    float* __restrict__ out, int N, int S) {
    int idx = blockIdx.x * 256 + threadIdx.x;
    int total = S * N;
    if (idx >= 4 * total) return;
    int q = idx / total;
    int r = idx - q * total;
    int s = r / N, v = r - s * N;
    const float* ip = in + (size_t)s * 64 * N + v;
    float acc[16];
#pragma unroll
    for (int o = 0; o < 16; ++o) acc[o] = 0.f;
    for (int ic = 0; ic < 64; ++ic) {
        float val = ip[(size_t)ic * N];
        const float* wr = wt + ic * 64 + q * 16;
#pragma unroll
        for (int o = 0; o < 16; ++o)
            acc[o] = fmaf(val, wr[o], acc[o]);
    }
    float* op = out + ((size_t)s * 64 + q * 16) * N + v;
#pragma unroll
    for (int o = 0; o < 16; ++o) op[(size_t)o * N] = acc[o];
}

// ---------------------------------------------------------------------------
// fused 1x1 convs k AND v from one nbb read. 16 oc each per thread.
// ---------------------------------------------------------------------------
__global__ void conv1x1_kv_kernel(const float* __restrict__ in,   // (6,64,ND)
                                  const float* __restrict__ wtk,
                                  const float* __restrict__ wtv,
                                  float* __restrict__ kout,
                                  float* __restrict__ vout) {
    int idx = blockIdx.x * 256 + threadIdx.x;
    if (idx >= 24 * ND) return;
    int v = idx % ND;
    int r = idx / ND;
    int s = r % 6;
    int q = r / 6;
    const float* ip = in + (size_t)s * 64 * ND + v;
    float ak[16], av[16];
#pragma unroll
    for (int o = 0; o < 16; ++o) { ak[o] = 0.f; av[o] = 0.f; }
    for (int ic = 0; ic < 64; ++ic) {
        float x = ip[(size_t)ic * ND];
        const float* wkr = wtk + ic * 64 + q * 16;
        const float* wvr = wtv + ic * 64 + q * 16;
#pragma unroll
        for (int o = 0; o < 16; ++o) {
            ak[o] = fmaf(x, wkr[o], ak[o]);
            av[o] = fmaf(x, wvr[o], av[o]);
        }
    }
    float* kp = kout + ((size_t)s * 64 + q * 16) * ND + v;
    float* vp = vout + ((size_t)s * 64 + q * 16) * ND + v;
#pragma unroll
    for (int o = 0; o < 16; ++o) {
        kp[(size_t)o * ND] = ak[o];
        vp[(size_t)o * ND] = av[o];
    }
}

// transpose all eight 64x64 weight matrices: grid 8
__global__ void transpose_w4_kernel(const float* __restrict__ q,
                                    const float* __restrict__ k,
                                    const float* __restrict__ v,
                                    const float* __restrict__ o,
                                    float* __restrict__ wt) {
    int m = blockIdx.x;            // 0..7: family = m>>1 (Q,K,V,O), layer = m&1
    const float* src = (m < 2 ? q : m < 4 ? k : m < 6 ? v : o) + (m & 1) * 4096;
    float* dst = wt + (size_t)(m >> 1) * 8192 + (m & 1) * 4096;
    for (int i = threadIdx.x; i < 4096; i += 256) {
        int oc = i >> 6, ic = i & 63;
        dst[ic * 64 + oc] = src[oc * 64 + ic];
    }
}

// ---------------------------------------------------------------------------
// attention scores: one thread per (direction, voxel)
// ---------------------------------------------------------------------------
__global__ void attn_score_kernel(const float* __restrict__ qraw,
                                  const float* __restrict__ kraw,
                                  const float* __restrict__ qstats,
                                  const float* __restrict__ kstats,
                                  const float* __restrict__ gq, const float* __restrict__ bq,
                                  const float* __restrict__ gk, const float* __restrict__ bk,
                                  float* __restrict__ sc) {
    int idx = blockIdx.x * 256 + threadIdx.x;
    if (idx >= 6 * ND) return;
    int v = idx % ND;
    int n = idx / ND;
    const float* kp = kraw + (size_t)n * 64 * ND + v;
    const float* ks = kstats + n * 64;
    float s = 0.f;
#pragma unroll
    for (int c = 0; c < 64; ++c) {
        float qm = qstats[2 * (c >> 1)], qr = qstats[2 * (c >> 1) + 1];
        float qn = (qraw[(size_t)c * ND + v] - qm) * qr * gq[c] + bq[c];
        float km = ks[2 * (c >> 1)], kr = ks[2 * (c >> 1) + 1];
        float kn = (kp[(size_t)c * ND] - km) * kr * gk[c] + bk[c];
        s = fmaf(kn, qn, s);
    }
    sc[idx] = s * 0.125f;
}

// ---------------------------------------------------------------------------
// softmax over 6 + weighted aggregation of normalized v; 8 ch per thread
// ---------------------------------------------------------------------------
__global__ void attn_agg_kernel(const float* __restrict__ vraw,
                                const float* __restrict__ sc,
                                const float* __restrict__ vstats,
                                const float* __restrict__ gv, const float* __restrict__ bv,
                                float* __restrict__ agg) {
    int idx = blockIdx.x * 256 + threadIdx.x;
    if (idx >= 8 * ND) return;
    int v  = idx % ND;
    int cg = idx / ND;
    float scv[6];
#pragma unroll
    for (int n = 0; n < 6; ++n) scv[n] = sc[n * ND + v];
    float mx = scv[0];
#pragma unroll
    for (int n = 1; n < 6; ++n) mx = fmaxf(mx, scv[n]);
    float w[6], den = 0.f;
#pragma unroll
    for (int n = 0; n < 6; ++n) { w[n] = expf(scv[n] - mx); den += w[n]; }
    float inv = 1.f / den;
#pragma unroll
    for (int n = 0; n < 6; ++n) w[n] *= inv;
#pragma unroll
    for (int j = 0; j < 8; ++j) {
        int c = cg * 8 + j;
        float s = 0.f;
#pragma unroll
        for (int n = 0; n < 6; ++n) {
            const float* vs = vstats + n * 64;
            float m = vs[2 * (c >> 1)], r = vs[2 * (c >> 1) + 1];
            float vn = (vraw[((size_t)n * 64 + c) * ND + v] - m) * r * gv[c] + bv[c];
            s = fmaf(w[n], vn, s);
        }
        agg[(size_t)c * ND + v] = s;
    }
}

// ---------------------------------------------------------------------------
// fused: trilinear upsample + residual (lazy GN) + 1x1 conv Wo + GN partials.
// Block = 64 voxels x 4 oc-quarters. xv staged in LDS [64ch][65].
// ---------------------------------------------------------------------------
__global__ __launch_bounds__(256, 4)
void fused_out_kernel(const float* __restrict__ agg,
                      const float* __restrict__ xin,
                      const float* __restrict__ wt,   // (ic,oc)
                      float* __restrict__ Aout,
                      float* __restrict__ psum,       // [64][2304]
                      float* __restrict__ psq,
                      const float* __restrict__ pst,
                      const float* __restrict__ pg,
                      const float* __restrict__ pb) {
    __shared__ float xv[64 * 65];
    const int t  = threadIdx.x;
    const int vx = t & 63;
    const int q  = t >> 6;
    const int v  = blockIdx.x * 64 + vx;
    const int z  = v & 15;
    const int y  = (v >> 4) % NY;
    const int x  = v / (16 * NY);

    float cx = fminf(fmaxf(0.5f * x - 0.25f, 0.f), 47.f);
    float cy = fminf(fmaxf(0.5f * y - 0.25f, 0.f), 47.f);
    float cz = fminf(fmaxf(0.5f * z - 0.25f, 0.f), 7.f);
    int x0 = (int)floorf(cx); int x1 = min(x0 + 1, 47); float fx = cx - x0;
    int y0 = (int)floorf(cy); int y1 = min(y0 + 1, 47); float fy = cy - y0;
    int z0 = (int)floorf(cz); int z1 = min(z0 + 1, 7);  float fz = cz - z0;

    int   lin[8];
    float w8[8];
    lin[0] = (x0 * SY + y0) * SZ + z0;  w8[0] = (1.f - fx) * (1.f - fy) * (1.f - fz);
    lin[1] = (x0 * SY + y0) * SZ + z1;  w8[1] = (1.f - fx) * (1.f - fy) * fz;
    lin[2] = (x0 * SY + y1) * SZ + z0;  w8[2] = (1.f - fx) * fy * (1.f - fz);
    lin[3] = (x0 * SY + y1) * SZ + z1;  w8[3] = (1.f - fx) * fy * fz;
    lin[4] = (x1 * SY + y0) * SZ + z0;  w8[4] = fx * (1.f - fy) * (1.f - fz);
    lin[5] = (x1 * SY + y0) * SZ + z1;  w8[5] = fx * (1.f - fy) * fz;
    lin[6] = (x1 * SY + y1) * SZ + z0;  w8[6] = fx * fy * (1.f - fz);
    lin[7] = (x1 * SY + y1) * SZ + z1;  w8[7] = fx * fy * fz;

#pragma unroll
    for (int j = 0; j < 16; ++j) {
        int c = q * 16 + j;
        const float* ap = agg + (size_t)c * ND;
        float s = 0.f;
#pragma unroll
        for (int k = 0; k < 8; ++k) s = fmaf(ap[lin[k]], w8[k], s);
        float xr = xin[(size_t)c * XYZ + v];
        if (pst) {
            float m = pst[2 * (c >> 1)], rr = pst[2 * (c >> 1) + 1];
            xr = (xr - m) * rr * pg[c] + pb[c];
        }
        xv[c * 65 + vx] = s + xr;
    }
    __syncthreads();

    float acc[16];
#pragma unroll
    for (int o = 0; o < 16; ++o) acc[o] = 0.f;
    for (int ic = 0; ic < 64; ++ic) {
        float val = xv[ic * 65 + vx];
        const float* wr = wt + ic * 64 + q * 16;
#pragma unroll
        for (int o = 0; o < 16; ++o)
            acc[o] = fmaf(val, wr[o], acc[o]);
    }
#pragma unroll
    for (int o = 0; o < 16; ++o)
        Aout[(size_t)(q * 16 + o) * XYZ + v] = acc[o];

    float rs[16], rq[16];
#pragma unroll
    for (int o = 0; o < 16; ++o) { rs[o] = acc[o]; rq[o] = acc[o] * acc[o]; }
#pragma unroll
    for (int d = 1; d < 64; d <<= 1) {
#pragma unroll
        for (int o = 0; o < 16; ++o) {
            rs[o] += __shfl_xor(rs[o], d);
            rq[o] += __shfl_xor(rq[o], d);
        }
    }
    if (vx == 0) {
#pragma unroll
        for (int o = 0; o < 16; ++o) {
            psum[(size_t)(q * 16 + o) * 2304 + blockIdx.x] = rs[o];
            psq [(size_t)(q * 16 + o) * 2304 + blockIdx.x] = rq[o];
        }
    }
}

// ---------------------------------------------------------------------------
extern "C" void kernel_launch(void* const* d_in, const int* in_sizes, int n_in,
                              void* d_out, int out_size, void* d_ws, size_t ws_size,
                              hipStream_t stream) {
    (void)in_sizes; (void)n_in; (void)out_size; (void)ws_size;
    const float* cls_feat  = (const float*)d_in[0];
    const float* box_feat  = (const float*)d_in[1];
    const float* bbox_W1   = (const float*)d_in[2];
    const float* bbox_gn_g = (const float*)d_in[3];
    const float* bbox_gn_b = (const float*)d_in[4];
    const float* bbox_W2   = (const float*)d_in[5];
    const float* cls_W1    = (const float*)d_in[6];
    const float* cls_gn_g  = (const float*)d_in[7];
    const float* cls_gn_b  = (const float*)d_in[8];
    const float* cls_W2    = (const float*)d_in[9];
    const float* rWq       = (const float*)d_in[10];
    const float* rWk       = (const float*)d_in[11];
    const float* rWv       = (const float*)d_in[12];
    const float* rWo       = (const float*)d_in[13];
    const float* r_gn_g    = (const float*)d_in[14];  // (2,4,64)
    const float* r_gn_b    = (const float*)d_in[15];

    float* out_cls  = (float*)d_out;          // (18,96,96,16)
    float* out_bbox = out_cls + 18 * XYZ;     // (6,96,96,16)

    float* ws    = (float*)d_ws;
    float* A     = ws;                        // 64*XYZ : evolving x (raw, pre-GN)
    float* Bf    = A + (size_t)64 * XYZ;      // 64*XYZ : scratch (scores + partials)
    float* xdb   = Bf + (size_t)64 * XYZ;     // 64*ND
    float* qb    = xdb + (size_t)64 * ND;     // 64*ND
    float* aggb  = qb + (size_t)64 * ND;      // 64*ND
    float* offs  = aggb + (size_t)64 * ND;    // 6*ND
    float* stats = offs + (size_t)6 * ND;     // 1024
    float* wts   = stats + 1024;              // 8*4096
    float* nbb   = wts + 8 * 4096;            // 6*64*ND
    float* krb   = nbb + (size_t)6 * 64 * ND; // 6*64*ND
    float* vrb   = krb + (size_t)6 * 64 * ND; // 6*64*ND
    float* hbuf  = vrb;                       // conv3x3 output region (32*XYZ)
    float* scb   = Bf;                        // 6*ND score scratch
    float* psum  = Bf + 200000;               // partial sums (up to 64*2304)
    float* psq   = psum + (size_t)64 * 2304;

    transpose_w4_kernel<<<8, 256, 0, stream>>>(rWq, rWk, rWv, rWo, wts);

    dim3 cgrid(24, 24, 4), cblk(16, 4, 4);

    // ---- bbox branch ----
    conv3x3_kernel<0><<<cgrid, cblk, 0, stream>>>(box_feat, bbox_W1,
                                                  nullptr, nullptr, nullptr,
                                                  hbuf, psum, psq);
    gn_stage2_kernel<<<32, 256, 0, stream>>>(psum, psq, stats, 576, 1, (float)XYZ);
    head_kernel<6><<<(XYZ + 255) / 256, 256, 0, stream>>>(hbuf, stats, bbox_gn_g,
                                                          bbox_gn_b, bbox_W2, out_bbox);
    downsample_kernel<<<(6 * SX * SY + 255) / 256, 256, 0, stream>>>(
        out_bbox, offs, 6 * SX * SY, 1, nullptr, nullptr, nullptr);

    // ---- refine stack (2 layers); x kept RAW with deferred out-GN ----
    const float* xcur = cls_feat;
    for (int l = 0; l < 2; ++l) {
        const float* gq = r_gn_g + (l * 4 + 0) * 64; const float* bq = r_gn_b + (l * 4 + 0) * 64;
        const float* gk = r_gn_g + (l * 4 + 1) * 64; const float* bk = r_gn_b + (l * 4 + 1) * 64;
        const float* gv = r_gn_g + (l * 4 + 2) * 64; const float* bv = r_gn_b + (l * 4 + 2) * 64;
        const float* pst = l ? stats + 896 : nullptr;   // layer0 out-GN stats
        const float* pg  = r_gn_g + 3 * 64;
        const float* pb  = r_gn_b + 3 * 64;

        downsample_kernel<<<(64 * SX * SY + 255) / 256, 256, 0, stream>>>(
            xcur, xdb, 64 * SX * SY, 0, pst, pg, pb);
        gridsample_kernel<<<(48 * ND + 255) / 256, 256, 0, stream>>>(xdb, offs, nbb);
        conv1x1_oc16_kernel<<<(4 * ND + 255) / 256, 256, 0, stream>>>(
            xdb, wts + l * 4096, qb, ND, 1);
        conv1x1_kv_kernel<<<(24 * ND + 255) / 256, 256, 0, stream>>>(
            nbb, wts + 8192 + l * 4096, wts + 16384 + l * 4096, krb, vrb);
        gn_stats3_kernel<<<416, 256, 0, stream>>>(qb, krb, vrb, stats);
        attn_score_kernel<<<(6 * ND + 255) / 256, 256, 0, stream>>>(
            qb, krb, stats + 64, stats + 128, gq, bq, gk, bk, scb);
        attn_agg_kernel<<<(8 * ND + 255) / 256, 256, 0, stream>>>(
            vrb, scb, stats + 512, gv, bv, aggb);
        fused_out_kernel<<<XYZ / 64, 256, 0, stream>>>(
            aggb, xcur, wts + 24576 + l * 4096, A, psum, psq, pst, pg, pb);
        gn_stage2_kernel<<<32, 256, 0, stream>>>(
            psum, psq, stats + 896 + l * 64, 2304, 2, (float)(2 * XYZ));
        xcur = A;
    }

    // ---- cls branch (GN of layer-1 output fused into conv staging) ----
    conv3x3_kernel<1><<<cgrid, cblk, 0, stream>>>(A, cls_W1, stats + 960,
                                                  r_gn_g + 7 * 64, r_gn_b + 7 * 64,
                                                  hbuf, psum, psq);
    gn_stage2_kernel<<<32, 256, 0, stream>>>(psum, psq, stats, 576, 1, (float)XYZ);
    head_kernel<18><<<(XYZ + 255) / 256, 256, 0, stream>>>(hbuf, stats, cls_gn_g,
                                                           cls_gn_b, cls_W2, out_cls);
}

// Round 12
// 1238.017 us; speedup vs baseline: 1.8194x; 1.3071x over previous
//
#include <hip/hip_runtime.h>
#include <cmath>

// Problem constants
#define NX 96
#define NY 96
#define NZ 16
#define XYZ (NX*NY*NZ)      // 147456
#define SX 48
#define SY 48
#define SZ 8
#define ND (SX*SY*SZ)       // 18432
#define CH 64
#define EPS_D 1e-5

// DPP row shifts within 16-lane rows; bound_ctrl=true -> 0-fill at row edge,
// which matches the conv's z=-1 / z=16 zero padding exactly.
__device__ __forceinline__ float dpp_shr1(float v) {   // lane n <- lane n-1
    return __int_as_float(__builtin_amdgcn_update_dpp(
        0, __float_as_int(v), 0x111, 0xF, 0xF, true));
}
__device__ __forceinline__ float dpp_shl1(float v) {   // lane n <- lane n+1
    return __int_as_float(__builtin_amdgcn_update_dpp(
        0, __float_as_int(v), 0x101, 0xF, 0xF, true));
}

// ---------------------------------------------------------------------------
// transpose conv weights (32,64,27) -> (64,27,32) oc-innermost, so the 8
// oc-weights of one tap are one aligned s_load_dwordx8.
// ---------------------------------------------------------------------------
__global__ void transpose_conv_w_kernel(const float* __restrict__ w,
                                        float* __restrict__ wt) {
    int idx = blockIdx.x * 256 + threadIdx.x;   // 216 blocks -> 55296
    if (idx >= 32 * 64 * 27) return;
    int oc = idx & 31;
    int r  = idx >> 5;
    int k  = r % 27;
    int ic = r / 27;
    wt[idx] = w[((size_t)oc * 64 + ic) * 27 + k];
}

// ---------------------------------------------------------------------------
// conv3x3 (64 -> 32), stride 1, SAME padding, no bias. 8 oc per block.
// block (16,4,4) = 256 threads; tile 4x4x16 outputs; grid (24,24,4) = 2304
// (r8-proven: >= 9 blocks/CU mandatory for this barrier-serialized loop).
// r10: z-taps via DPP (conflict-free 4.6KB LDS). r11: (a) weights in
// [ic][27][32] layout -> s_load_dwordx8 per tap (54 SMEM ops/round, was 432
// s_load_dword); (b) all 18 ds_reads hoisted to round start so the FMA
// stream has no LDS ops -> no cross-pipe lgkmcnt(0) flushes (SMEM is
// out-of-order on CDNA; mixing it with ds_read forces full flushes).
// Register double-buffer (r8). Epilogue: GN partial sums.
// ---------------------------------------------------------------------------
template <int NORM>
__global__ __launch_bounds__(256, 8)
void conv3x3_kernel(const float* __restrict__ in,
                    const float* __restrict__ wt,  // (64,27,32) transposed
                    const float* __restrict__ stats,
                    const float* __restrict__ gamma,
                    const float* __restrict__ beta,
                    float* __restrict__ out,
                    float* __restrict__ psum,      // [32][576]
                    float* __restrict__ psq) {
    __shared__ float sm[2 * 576];
    const int tz = threadIdx.x;          // 0..15 (= lane & 15)
    const int ty = threadIdx.y;          // 0..3
    const int tx = threadIdx.z;          // 0..3 (= wave id)
    const int x0 = blockIdx.x * 4;
    const int y0 = blockIdx.y * 4;
    const int oc0 = blockIdx.z * 8;
    const int t = tz + 16 * ty + 64 * tx;

    // staging: 288 float4 quads (2 planes x 144 each).
    int lds0, gof0, lds1, gof1, p0;
    bool v0, w1, v1;
    {
        int qi = t;
        p0 = qi >= 144 ? 1 : 0;
        int rc = qi - p0 * 144;          // 0..143
        int col = rc >> 2, qz = rc & 3;
        int lx = col / 6, ly = col - lx * 6;
        lds0 = p0 * 576 + rc * 4;
        int ix = x0 + lx - 1, iy = y0 + ly - 1;
        v0 = ((unsigned)ix < NX) && ((unsigned)iy < NY);
        gof0 = (ix * NY + iy) * NZ + qz * 4 + (p0 ? XYZ : 0);
    }
    {
        int rc = 112 + t;                // plane 1, quads 112..143
        int col = rc >> 2, qz = rc & 3;
        int lx = col / 6, ly = col - lx * 6;
        lds1 = 576 + rc * 4;
        int ix = x0 + lx - 1, iy = y0 + ly - 1;
        w1 = (t < 32);
        v1 = w1 && ((unsigned)ix < NX) && ((unsigned)iy < NY);
        gof1 = (ix * NY + iy) * NZ + qz * 4 + XYZ;
    }

    // prologue: issue loads for round 0 immediately
    float4 a0 = {0.f, 0.f, 0.f, 0.f}, a1 = {0.f, 0.f, 0.f, 0.f};
    if (v0) a0 = *(const float4*)(in + gof0);
    if (v1) a1 = *(const float4*)(in + gof1);

    float acc[8];
#pragma unroll
    for (int o = 0; o < 8; ++o) acc[o] = 0.f;

    const int rbase = tx * 96 + ty * 16 + tz;

    for (int ic0 = 0; ic0 < 64; ic0 += 2) {
        float s0 = 1.f, h0 = 0.f, s1 = 1.f, h1 = 0.f;
        if (NORM) {   // ic0 even: ic0, ic0+1 share a group (2 ch/group)
            float m = stats[ic0], r = stats[ic0 + 1];
            s0 = gamma[ic0] * r;     h0 = beta[ic0] - m * s0;
            s1 = gamma[ic0 + 1] * r; h1 = beta[ic0 + 1] - m * s1;
        }
        __syncthreads();   // previous round's LDS reads done before overwrite
        float4 wa0 = a0, wa1 = a1;
        if (NORM) {
            float sc = p0 ? s1 : s0, sh = p0 ? h1 : h0;
            if (v0) {
                wa0.x = fmaf(a0.x, sc, sh); wa0.y = fmaf(a0.y, sc, sh);
                wa0.z = fmaf(a0.z, sc, sh); wa0.w = fmaf(a0.w, sc, sh);
            }
            if (v1) {
                wa1.x = fmaf(a1.x, s1, h1); wa1.y = fmaf(a1.y, s1, h1);
                wa1.z = fmaf(a1.z, s1, h1); wa1.w = fmaf(a1.w, s1, h1);
            }
        }
        *(float4*)(sm + lds0) = wa0;
        if (w1) *(float4*)(sm + lds1) = wa1;

        // prefetch next round into registers (latency hides under compute)
        float4 b0 = {0.f, 0.f, 0.f, 0.f}, b1 = {0.f, 0.f, 0.f, 0.f};
        if (ic0 + 2 < 64) {
            const float* nbase = in + (size_t)(ic0 + 2) * XYZ;
            if (v0) b0 = *(const float4*)(nbase + gof0);
            if (v1) b1 = *(const float4*)(nbase + gof1);
        }
        __syncthreads();   // LDS writes visible

        // ---- hoist ALL ds_reads of this round into registers (in-order
        // lgkmcnt(N) waits; the FMA stream below then has SMEM only) ----
        float vin[2][9];
#pragma unroll
        for (int p = 0; p < 2; ++p)
#pragma unroll
            for (int dx = 0; dx < 3; ++dx)
#pragma unroll
                for (int dy = 0; dy < 3; ++dy)
                    vin[p][dx * 3 + dy] = sm[p * 576 + rbase + dx * 96 + dy * 16];

#pragma unroll
        for (int p = 0; p < 2; ++p) {
            // weight base for this ic plane: taps k in [0,27), oc-innermost
            const float* wp = wt + ((size_t)(ic0 + p) * 27) * 32 + oc0;
#pragma unroll
            for (int e = 0; e < 9; ++e) {
                float v  = vin[p][e];
                float vm = dpp_shr1(v);   // in[z-1] (0-fill = z pad)
                float vp = dpp_shl1(v);   // in[z+1]
                const int kb = (e / 3) * 9 + (e % 3) * 3;   // dx*9+dy*3
                const float* wk = wp + kb * 32;
#pragma unroll
                for (int o = 0; o < 8; ++o) {
                    acc[o] = fmaf(vm, wk[o],      acc[o]);
                    acc[o] = fmaf(v,  wk[32 + o], acc[o]);
                    acc[o] = fmaf(vp, wk[64 + o], acc[o]);
                }
            }
        }
        a0 = b0; a1 = b1;
    }

    const int gx = x0 + tx, gy = y0 + ty;
    const int vofs = (gx * NY + gy) * NZ + tz;
#pragma unroll
    for (int o = 0; o < 8; ++o)
        out[(size_t)(oc0 + o) * XYZ + vofs] = acc[o];

    // ---- per-block GroupNorm partial sums ----
    float rs[8], rq[8];
#pragma unroll
    for (int o = 0; o < 8; ++o) { rs[o] = acc[o]; rq[o] = acc[o] * acc[o]; }
#pragma unroll
    for (int d = 1; d < 64; d <<= 1) {
#pragma unroll
        for (int o = 0; o < 8; ++o) {
            rs[o] += __shfl_xor(rs[o], d);
            rq[o] += __shfl_xor(rq[o], d);
        }
    }
    __syncthreads();           // all sm reads done; reuse as reduction buffer
    const int lane = tz + 16 * ty;
    if (lane == 0) {
#pragma unroll
        for (int o = 0; o < 8; ++o) {
            sm[tx * 16 + o]     = rs[o];
            sm[tx * 16 + 8 + o] = rq[o];
        }
    }
    __syncthreads();
    if (t < 16) {
        int o = t & 7;
        int base = (t & 8);
        float tot = sm[base + o] + sm[16 + base + o] + sm[32 + base + o] + sm[48 + base + o];
        int bflat = blockIdx.y * 24 + blockIdx.x;
        if (t < 8) psum[(size_t)(oc0 + o) * 576 + bflat] = tot;
        else       psq [(size_t)(oc0 + o) * 576 + bflat] = tot;
    }
}

// ---------------------------------------------------------------------------
// stage-2 reduction of GroupNorm partials.
// ---------------------------------------------------------------------------
__global__ void gn_stage2_kernel(const float* __restrict__ psum,
                                 const float* __restrict__ psq,
                                 float* __restrict__ stats,
                                 int nblocks, int cpg, float gsize) {
    const int g = blockIdx.x;
    const int n = cpg * nblocks;
    const size_t off = (size_t)g * n;
    double s = 0.0, ss = 0.0;
    for (int i = threadIdx.x; i < n; i += blockDim.x) {
        s  += (double)psum[off + i];
        ss += (double)psq[off + i];
    }
    for (int d = 32; d > 0; d >>= 1) {
        s  += __shfl_down(s, d);
        ss += __shfl_down(ss, d);
    }
    __shared__ double shs[4], shss[4];
    const int lane = threadIdx.x & 63, wid = threadIdx.x >> 6;
    if (lane == 0) { shs[wid] = s; shss[wid] = ss; }
    __syncthreads();
    if (threadIdx.x == 0) {
        double S = 0.0, SS = 0.0;
        for (int i = 0; i < 4; ++i) { S += shs[i]; SS += shss[i]; }
        double m = S / gsize;
        double var = SS / gsize - m * m;
        stats[2 * g]     = (float)m;
        stats[2 * g + 1] = (float)(1.0 / sqrt(var + EPS_D));
    }
}

// ---------------------------------------------------------------------------
// fused GroupNorm stats for q (32 groups), k (192), v (192): 416 blocks.
// ---------------------------------------------------------------------------
__global__ void gn_stats3_kernel(const float* __restrict__ qb,
                                 const float* __restrict__ kb,
                                 const float* __restrict__ vb,
                                 float* __restrict__ stats) {
    const int b = blockIdx.x;
    const float* src;
    float* dst;
    int g;
    if (b < 32)       { src = qb; g = b;       dst = stats + 64;  }
    else if (b < 224) { src = kb; g = b - 32;  dst = stats + 128; }
    else              { src = vb; g = b - 224; dst = stats + 512; }
    const float4* p = (const float4*)(src + (size_t)g * (2 * ND));
    double s = 0.0, ss = 0.0;
    for (int i = threadIdx.x; i < (2 * ND) / 4; i += 256) {
        float4 x = p[i];
        s  += (double)x.x + (double)x.y + (double)x.z + (double)x.w;
        ss += (double)x.x * x.x + (double)x.y * x.y +
              (double)x.z * x.z + (double)x.w * x.w;
    }
    for (int d = 32; d > 0; d >>= 1) {
        s  += __shfl_down(s, d);
        ss += __shfl_down(ss, d);
    }
    __shared__ double shs[4], shss[4];
    const int lane = threadIdx.x & 63, wid = threadIdx.x >> 6;
    if (lane == 0) { shs[wid] = s; shss[wid] = ss; }
    __syncthreads();
    if (threadIdx.x == 0) {
        double S = 0.0, SS = 0.0;
        for (int i = 0; i < 4; ++i) { S += shs[i]; SS += shss[i]; }
        double m = S / (2.0 * ND);
        double var = SS / (2.0 * ND) - m * m;
        dst[2 * g]     = (float)m;
        dst[2 * g + 1] = (float)(1.0 / sqrt(var + EPS_D));
    }
}

// ---------------------------------------------------------------------------
// fused: GroupNorm(32ch, 32 groups) -> ReLU -> 1x1 conv (32 -> NOUT)
// ---------------------------------------------------------------------------
template <int NOUT>
__global__ void head_kernel(const float* __restrict__ h,
                            const float* __restrict__ stats,
                            const float* __restrict__ gamma,
                            const float* __restrict__ beta,
                            const float* __restrict__ w2,   // (NOUT,32)
                            float* __restrict__ out) {
    const int v = blockIdx.x * 256 + threadIdx.x;
    if (v >= XYZ) return;
    float acc[NOUT];
#pragma unroll
    for (int o = 0; o < NOUT; ++o) acc[o] = 0.f;
#pragma unroll
    for (int ic = 0; ic < 32; ++ic) {
        float m = stats[2 * ic], r = stats[2 * ic + 1];
        float val = (h[(size_t)ic * XYZ + v] - m) * r * gamma[ic] + beta[ic];
        val = fmaxf(val, 0.f);
#pragma unroll
        for (int o = 0; o < NOUT; ++o)
            acc[o] = fmaf(val, w2[o * 32 + ic], acc[o]);
    }
#pragma unroll
    for (int o = 0; o < NOUT; ++o) out[(size_t)o * XYZ + v] = acc[o];
}

// ---------------------------------------------------------------------------
// trilinear downsample (exact 2x2x2 average), float4-vectorized.
// ---------------------------------------------------------------------------
__global__ void downsample_kernel(const float* __restrict__ in,
                                  float* __restrict__ out, int totalCols,
                                  int applySigmoid,
                                  const float* __restrict__ stats,
                                  const float* __restrict__ gamma,
                                  const float* __restrict__ beta) {
    int idx = blockIdx.x * 256 + threadIdx.x;
    if (idx >= totalCols) return;
    int b  = idx % SY;
    int r  = idx / SY;
    int a  = r % SX;
    int ch = r / SX;
    const float4* r0 = (const float4*)(in + (((size_t)ch * NX + 2 * a) * NY + 2 * b) * NZ);
    const float4* r1 = (const float4*)(in + (((size_t)ch * NX + 2 * a + 1) * NY + 2 * b) * NZ);
    float sc = 1.f, sh = 0.f;
    if (stats) {
        float m = stats[2 * (ch >> 1)], rr = stats[2 * (ch >> 1) + 1];
        sc = rr * gamma[ch];
        sh = beta[ch] - m * sc;
    }
    float o8[8];
#pragma unroll
    for (int q = 0; q < 4; ++q) {
        float4 A = r0[q], B = r0[q + 4], C = r1[q], D = r1[q + 4];
        float e0 = (A.x + A.y + B.x + B.y + C.x + C.y + D.x + D.y) * 0.125f;
        float e1 = (A.z + A.w + B.z + B.w + C.z + C.w + D.z + D.w) * 0.125f;
        if (stats) { e0 = fmaf(e0, sc, sh); e1 = fmaf(e1, sc, sh); }
        if (applySigmoid) {
            e0 = 1.f / (1.f + expf(-e0));
            e1 = 1.f / (1.f + expf(-e1));
        }
        o8[2 * q] = e0; o8[2 * q + 1] = e1;
    }
    float* op = out + (((size_t)ch * SX + a) * SY + b) * SZ;
    *(float4*)op       = make_float4(o8[0], o8[1], o8[2], o8[3]);
    *(float4*)(op + 4) = make_float4(o8[4], o8[5], o8[6], o8[7]);
}

// ---------------------------------------------------------------------------
// fused generate_grids + grid_sample; 8 channels per thread.
// ---------------------------------------------------------------------------
__global__ void gridsample_kernel(const float* __restrict__ xd,
                                  const float* __restrict__ offs,
                                  float* __restrict__ nb) {
    int idx = blockIdx.x * 256 + threadIdx.x;
    if (idx >= 48 * ND) return;
    int vox = idx % ND;
    int t2  = idx / ND;
    int cg  = t2 & 7;
    int n   = t2 >> 3;
    int c2  = vox & 7;
    int b   = (vox >> 3) % SY;
    int a   = vox / (8 * SY);
    float o = offs[n * ND + vox];

    float sx = (float)a, sy = (float)b, sz = (float)c2;
    switch (n) {
        case 0: sx = fminf(fmaxf(sx + o * 47.f, 0.f), 47.f); break;
        case 1: sx = fminf(fmaxf(sx - o * 47.f, 0.f), 47.f); break;
        case 2: sy = fminf(fmaxf(sy + o * 47.f, 0.f), 47.f); break;
        case 3: sy = fminf(fmaxf(sy - o * 47.f, 0.f), 47.f); break;
        case 4: sz = fminf(fmaxf(sz + o * 7.f, 0.f), 7.f); break;
        default: sz = fminf(fmaxf(sz - o * 7.f, 0.f), 7.f); break;
    }
    float u0 = 2.f * sx / 47.f - 1.f;
    float u1 = 2.f * sy / 47.f - 1.f;
    float u2 = 2.f * sz / 7.f - 1.f;
    // torch grid_sample: comp0 -> W axis (=SZ), comp1 -> H (=SY), comp2 -> D (=SX)
    float ix = ((u0 + 1.f) * (float)SZ - 1.f) * 0.5f;
    float iy = ((u1 + 1.f) * (float)SY - 1.f) * 0.5f;
    float iz = ((u2 + 1.f) * (float)SX - 1.f) * 0.5f;
    float x0f = floorf(ix), y0f = floorf(iy), z0f = floorf(iz);
    float wx = ix - x0f, wy = iy - y0f, wz = iz - z0f;
    int x0 = (int)x0f, y0 = (int)y0f, z0 = (int)z0f;

    int   lin[8];
    float wt[8];
#pragma unroll
    for (int t = 0; t < 8; ++t) {
        int dx = t & 1, dy = (t >> 1) & 1, dz = (t >> 2) & 1;
        int xc = x0 + dx, yc = y0 + dy, zc = z0 + dz;
        bool valid = (xc >= 0 && xc < SZ && yc >= 0 && yc < SY && zc >= 0 && zc < SX);
        int xcc = min(max(xc, 0), SZ - 1);
        int ycc = min(max(yc, 0), SY - 1);
        int zcc = min(max(zc, 0), SX - 1);
        lin[t] = (zcc * SY + ycc) * SZ + xcc;
        wt[t] = (dx ? wx : 1.f - wx) * (dy ? wy : 1.f - wy) * (dz ? wz : 1.f - wz)
                * (valid ? 1.f : 0.f);
    }
    float* op = nb + ((size_t)n * CH + cg * 8) * ND + vox;
#pragma unroll
    for (int j = 0; j < 8; ++j) {
        const float* vp = xd + (size_t)(cg * 8 + j) * ND;
        float s = 0.f;
#pragma unroll
        for (int t = 0; t < 8; ++t)
            if (wt[t] != 0.f) s = fmaf(vp[lin[t]], wt[t], s);
        op[(size_t)j * ND] = s;
    }
}

// ---------------------------------------------------------------------------
// 1x1 conv 64->64, 16 output channels per thread; wt transposed (ic,oc)
// ---------------------------------------------------------------------------
__global__ void conv1x1_oc16_kernel(const float* __restrict__ in,
                                    const float* __restrict__ wt,
                                    float* __restrict__ out, int N, int S) {
    int idx = blockIdx.x * 256 + threadIdx.x;
    int total = S * N;
    if (idx >= 4 * total) return;
    int q = idx / total;
    int r = idx - q * total;
    int s = r / N, v = r - s * N;
    const float* ip = in + (size_t)s * 64 * N + v;
    float acc[16];
#pragma unroll
    for (int o = 0; o < 16; ++o) acc[o] = 0.f;
    for (int ic = 0; ic < 64; ++ic) {
        float val = ip[(size_t)ic * N];
        const float* wr = wt + ic * 64 + q * 16;
#pragma unroll
        for (int o = 0; o < 16; ++o)
            acc[o] = fmaf(val, wr[o], acc[o]);
    }
    float* op = out + ((size_t)s * 64 + q * 16) * N + v;
#pragma unroll
    for (int o = 0; o < 16; ++o) op[(size_t)o * N] = acc[o];
}

// ---------------------------------------------------------------------------
// fused 1x1 convs k AND v from one nbb read. 16 oc each per thread.
// ---------------------------------------------------------------------------
__global__ void conv1x1_kv_kernel(const float* __restrict__ in,   // (6,64,ND)
                                  const float* __restrict__ wtk,
                                  const float* __restrict__ wtv,
                                  float* __restrict__ kout,
                                  float* __restrict__ vout) {
    int idx = blockIdx.x * 256 + threadIdx.x;
    if (idx >= 24 * ND) return;
    int v = idx % ND;
    int r = idx / ND;
    int s = r % 6;
    int q = r / 6;
    const float* ip = in + (size_t)s * 64 * ND + v;
    float ak[16], av[16];
#pragma unroll
    for (int o = 0; o < 16; ++o) { ak[o] = 0.f; av[o] = 0.f; }
    for (int ic = 0; ic < 64; ++ic) {
        float x = ip[(size_t)ic * ND];
        const float* wkr = wtk + ic * 64 + q * 16;
        const float* wvr = wtv + ic * 64 + q * 16;
#pragma unroll
        for (int o = 0; o < 16; ++o) {
            ak[o] = fmaf(x, wkr[o], ak[o]);
            av[o] = fmaf(x, wvr[o], av[o]);
        }
    }
    float* kp = kout + ((size_t)s * 64 + q * 16) * ND + v;
    float* vp = vout + ((size_t)s * 64 + q * 16) * ND + v;
#pragma unroll
    for (int o = 0; o < 16; ++o) {
        kp[(size_t)o * ND] = ak[o];
        vp[(size_t)o * ND] = av[o];
    }
}

// transpose all eight 64x64 weight matrices: grid 8
__global__ void transpose_w4_kernel(const float* __restrict__ q,
                                    const float* __restrict__ k,
                                    const float* __restrict__ v,
                                    const float* __restrict__ o,
                                    float* __restrict__ wt) {
    int m = blockIdx.x;            // 0..7: family = m>>1 (Q,K,V,O), layer = m&1
    const float* src = (m < 2 ? q : m < 4 ? k : m < 6 ? v : o) + (m & 1) * 4096;
    float* dst = wt + (size_t)(m >> 1) * 8192 + (m & 1) * 4096;
    for (int i = threadIdx.x; i < 4096; i += 256) {
        int oc = i >> 6, ic = i & 63;
        dst[ic * 64 + oc] = src[oc * 64 + ic];
    }
}

// ---------------------------------------------------------------------------
// attention scores: one thread per (direction, voxel)
// ---------------------------------------------------------------------------
__global__ void attn_score_kernel(const float* __restrict__ qraw,
                                  const float* __restrict__ kraw,
                                  const float* __restrict__ qstats,
                                  const float* __restrict__ kstats,
                                  const float* __restrict__ gq, const float* __restrict__ bq,
                                  const float* __restrict__ gk, const float* __restrict__ bk,
                                  float* __restrict__ sc) {
    int idx = blockIdx.x * 256 + threadIdx.x;
    if (idx >= 6 * ND) return;
    int v = idx % ND;
    int n = idx / ND;
    const float* kp = kraw + (size_t)n * 64 * ND + v;
    const float* ks = kstats + n * 64;
    float s = 0.f;
#pragma unroll
    for (int c = 0; c < 64; ++c) {
        float qm = qstats[2 * (c >> 1)], qr = qstats[2 * (c >> 1) + 1];
        float qn = (qraw[(size_t)c * ND + v] - qm) * qr * gq[c] + bq[c];
        float km = ks[2 * (c >> 1)], kr = ks[2 * (c >> 1) + 1];
        float kn = (kp[(size_t)c * ND] - km) * kr * gk[c] + bk[c];
        s = fmaf(kn, qn, s);
    }
    sc[idx] = s * 0.125f;
}

// ---------------------------------------------------------------------------
// softmax over 6 + weighted aggregation of normalized v; 8 ch per thread
// ---------------------------------------------------------------------------
__global__ void attn_agg_kernel(const float* __restrict__ vraw,
                                const float* __restrict__ sc,
                                const float* __restrict__ vstats,
                                const float* __restrict__ gv, const float* __restrict__ bv,
                                float* __restrict__ agg) {
    int idx = blockIdx.x * 256 + threadIdx.x;
    if (idx >= 8 * ND) return;
    int v  = idx % ND;
    int cg = idx / ND;
    float scv[6];
#pragma unroll
    for (int n = 0; n < 6; ++n) scv[n] = sc[n * ND + v];
    float mx = scv[0];
#pragma unroll
    for (int n = 1; n < 6; ++n) mx = fmaxf(mx, scv[n]);
    float w[6], den = 0.f;
#pragma unroll
    for (int n = 0; n < 6; ++n) { w[n] = expf(scv[n] - mx); den += w[n]; }
    float inv = 1.f / den;
#pragma unroll
    for (int n = 0; n < 6; ++n) w[n] *= inv;
#pragma unroll
    for (int j = 0; j < 8; ++j) {
        int c = cg * 8 + j;
        float s = 0.f;
#pragma unroll
        for (int n = 0; n < 6; ++n) {
            const float* vs = vstats + n * 64;
            float m = vs[2 * (c >> 1)], r = vs[2 * (c >> 1) + 1];
            float vn = (vraw[((size_t)n * 64 + c) * ND + v] - m) * r * gv[c] + bv[c];
            s = fmaf(w[n], vn, s);
        }
        agg[(size_t)c * ND + v] = s;
    }
}

// ---------------------------------------------------------------------------
// fused: trilinear upsample + residual (lazy GN) + 1x1 conv Wo + GN partials.
// ---------------------------------------------------------------------------
__global__ __launch_bounds__(256, 4)
void fused_out_kernel(const float* __restrict__ agg,
                      const float* __restrict__ xin,
                      const float* __restrict__ wt,   // (ic,oc)
                      float* __restrict__ Aout,
                      float* __restrict__ psum,       // [64][2304]
                      float* __restrict__ psq,
                      const float* __restrict__ pst,
                      const float* __restrict__ pg,
                      const float* __restrict__ pb) {
    __shared__ float xv[64 * 65];
    const int t  = threadIdx.x;
    const int vx = t & 63;
    const int q  = t >> 6;
    const int v  = blockIdx.x * 64 + vx;
    const int z  = v & 15;
    const int y  = (v >> 4) % NY;
    const int x  = v / (16 * NY);

    float cx = fminf(fmaxf(0.5f * x - 0.25f, 0.f), 47.f);
    float cy = fminf(fmaxf(0.5f * y - 0.25f, 0.f), 47.f);
    float cz = fminf(fmaxf(0.5f * z - 0.25f, 0.f), 7.f);
    int x0 = (int)floorf(cx); int x1 = min(x0 + 1, 47); float fx = cx - x0;
    int y0 = (int)floorf(cy); int y1 = min(y0 + 1, 47); float fy = cy - y0;
    int z0 = (int)floorf(cz); int z1 = min(z0 + 1, 7);  float fz = cz - z0;

    int   lin[8];
    float w8[8];
    lin[0] = (x0 * SY + y0) * SZ + z0;  w8[0] = (1.f - fx) * (1.f - fy) * (1.f - fz);
    lin[1] = (x0 * SY + y0) * SZ + z1;  w8[1] = (1.f - fx) * (1.f - fy) * fz;
    lin[2] = (x0 * SY + y1) * SZ + z0;  w8[2] = (1.f - fx) * fy * (1.f - fz);
    lin[3] = (x0 * SY + y1) * SZ + z1;  w8[3] = (1.f - fx) * fy * fz;
    lin[4] = (x1 * SY + y0) * SZ + z0;  w8[4] = fx * (1.f - fy) * (1.f - fz);
    lin[5] = (x1 * SY + y0) * SZ + z1;  w8[5] = fx * (1.f - fy) * fz;
    lin[6] = (x1 * SY + y1) * SZ + z0;  w8[6] = fx * fy * (1.f - fz);
    lin[7] = (x1 * SY + y1) * SZ + z1;  w8[7] = fx * fy * fz;

#pragma unroll
    for (int j = 0; j < 16; ++j) {
        int c = q * 16 + j;
        const float* ap = agg + (size_t)c * ND;
        float s = 0.f;
#pragma unroll
        for (int k = 0; k < 8; ++k) s = fmaf(ap[lin[k]], w8[k], s);
        float xr = xin[(size_t)c * XYZ + v];
        if (pst) {
            float m = pst[2 * (c >> 1)], rr = pst[2 * (c >> 1) + 1];
            xr = (xr - m) * rr * pg[c] + pb[c];
        }
        xv[c * 65 + vx] = s + xr;
    }
    __syncthreads();

    float acc[16];
#pragma unroll
    for (int o = 0; o < 16; ++o) acc[o] = 0.f;
    for (int ic = 0; ic < 64; ++ic) {
        float val = xv[ic * 65 + vx];
        const float* wr = wt + ic * 64 + q * 16;
#pragma unroll
        for (int o = 0; o < 16; ++o)
            acc[o] = fmaf(val, wr[o], acc[o]);
    }
#pragma unroll
    for (int o = 0; o < 16; ++o)
        Aout[(size_t)(q * 16 + o) * XYZ + v] = acc[o];

    float rs[16], rq[16];
#pragma unroll
    for (int o = 0; o < 16; ++o) { rs[o] = acc[o]; rq[o] = acc[o] * acc[o]; }
#pragma unroll
    for (int d = 1; d < 64; d <<= 1) {
#pragma unroll
        for (int o = 0; o < 16; ++o) {
            rs[o] += __shfl_xor(rs[o], d);
            rq[o] += __shfl_xor(rq[o], d);
        }
    }
    if (vx == 0) {
#pragma unroll
        for (int o = 0; o < 16; ++o) {
            psum[(size_t)(q * 16 + o) * 2304 + blockIdx.x] = rs[o];
            psq [(size_t)(q * 16 + o) * 2304 + blockIdx.x] = rq[o];
        }
    }
}

// ---------------------------------------------------------------------------
extern "C" void kernel_launch(void* const* d_in, const int* in_sizes, int n_in,
                              void* d_out, int out_size, void* d_ws, size_t ws_size,
                              hipStream_t stream) {
    (void)in_sizes; (void)n_in; (void)out_size; (void)ws_size;
    const float* cls_feat  = (const float*)d_in[0];
    const float* box_feat  = (const float*)d_in[1];
    const float* bbox_W1   = (const float*)d_in[2];
    const float* bbox_gn_g = (const float*)d_in[3];
    const float* bbox_gn_b = (const float*)d_in[4];
    const float* bbox_W2   = (const float*)d_in[5];
    const float* cls_W1    = (const float*)d_in[6];
    const float* cls_gn_g  = (const float*)d_in[7];
    const float* cls_gn_b  = (const float*)d_in[8];
    const float* cls_W2    = (const float*)d_in[9];
    const float* rWq       = (const float*)d_in[10];
    const float* rWk       = (const float*)d_in[11];
    const float* rWv       = (const float*)d_in[12];
    const float* rWo       = (const float*)d_in[13];
    const float* r_gn_g    = (const float*)d_in[14];  // (2,4,64)
    const float* r_gn_b    = (const float*)d_in[15];

    float* out_cls  = (float*)d_out;          // (18,96,96,16)
    float* out_bbox = out_cls + 18 * XYZ;     // (6,96,96,16)

    float* ws    = (float*)d_ws;
    float* A     = ws;                        // 64*XYZ : evolving x (raw, pre-GN)
    float* Bf    = A + (size_t)64 * XYZ;      // 64*XYZ : scratch region
    float* xdb   = Bf + (size_t)64 * XYZ;     // 64*ND
    float* qb    = xdb + (size_t)64 * ND;     // 64*ND
    float* aggb  = qb + (size_t)64 * ND;      // 64*ND
    float* offs  = aggb + (size_t)64 * ND;    // 6*ND
    float* stats = offs + (size_t)6 * ND;     // 1024
    float* wts   = stats + 1024;              // 8*4096
    float* nbb   = wts + 8 * 4096;            // 6*64*ND
    float* krb   = nbb + (size_t)6 * 64 * ND; // 6*64*ND
    float* vrb   = krb + (size_t)6 * 64 * ND; // 6*64*ND
    float* hbuf  = vrb;                       // conv3x3 output region (32*XYZ)
    float* scb   = Bf;                        // 6*ND score scratch
    float* psum  = Bf + 200000;               // partial sums (up to 64*2304)
    float* psq   = psum + (size_t)64 * 2304;
    float* cwtA  = psq + (size_t)64 * 2304;   // bbox conv weights (64,27,32)
    float* cwtB  = cwtA + 55296;              // cls conv weights

    transpose_w4_kernel<<<8, 256, 0, stream>>>(rWq, rWk, rWv, rWo, wts);
    transpose_conv_w_kernel<<<216, 256, 0, stream>>>(bbox_W1, cwtA);
    transpose_conv_w_kernel<<<216, 256, 0, stream>>>(cls_W1, cwtB);

    dim3 cgrid(24, 24, 4), cblk(16, 4, 4);

    // ---- bbox branch ----
    conv3x3_kernel<0><<<cgrid, cblk, 0, stream>>>(box_feat, cwtA,
                                                  nullptr, nullptr, nullptr,
                                                  hbuf, psum, psq);
    gn_stage2_kernel<<<32, 256, 0, stream>>>(psum, psq, stats, 576, 1, (float)XYZ);
    head_kernel<6><<<(XYZ + 255) / 256, 256, 0, stream>>>(hbuf, stats, bbox_gn_g,
                                                          bbox_gn_b, bbox_W2, out_bbox);
    downsample_kernel<<<(6 * SX * SY + 255) / 256, 256, 0, stream>>>(
        out_bbox, offs, 6 * SX * SY, 1, nullptr, nullptr, nullptr);

    // ---- refine stack (2 layers); x kept RAW with deferred out-GN ----
    const float* xcur = cls_feat;
    for (int l = 0; l < 2; ++l) {
        const float* gq = r_gn_g + (l * 4 + 0) * 64; const float* bq = r_gn_b + (l * 4 + 0) * 64;
        const float* gk = r_gn_g + (l * 4 + 1) * 64; const float* bk = r_gn_b + (l * 4 + 1) * 64;
        const float* gv = r_gn_g + (l * 4 + 2) * 64; const float* bv = r_gn_b + (l * 4 + 2) * 64;
        const float* pst = l ? stats + 896 : nullptr;   // layer0 out-GN stats
        const float* pg  = r_gn_g + 3 * 64;
        const float* pb  = r_gn_b + 3 * 64;

        downsample_kernel<<<(64 * SX * SY + 255) / 256, 256, 0, stream>>>(
            xcur, xdb, 64 * SX * SY, 0, pst, pg, pb);
        gridsample_kernel<<<(48 * ND + 255) / 256, 256, 0, stream>>>(xdb, offs, nbb);
        conv1x1_oc16_kernel<<<(4 * ND + 255) / 256, 256, 0, stream>>>(
            xdb, wts + l * 4096, qb, ND, 1);
        conv1x1_kv_kernel<<<(24 * ND + 255) / 256, 256, 0, stream>>>(
            nbb, wts + 8192 + l * 4096, wts + 16384 + l * 4096, krb, vrb);
        gn_stats3_kernel<<<416, 256, 0, stream>>>(qb, krb, vrb, stats);
        attn_score_kernel<<<(6 * ND + 255) / 256, 256, 0, stream>>>(
            qb, krb, stats + 64, stats + 128, gq, bq, gk, bk, scb);
        attn_agg_kernel<<<(8 * ND + 255) / 256, 256, 0, stream>>>(
            vrb, scb, stats + 512, gv, bv, aggb);
        fused_out_kernel<<<XYZ / 64, 256, 0, stream>>>(
            aggb, xcur, wts + 24576 + l * 4096, A, psum, psq, pst, pg, pb);
        gn_stage2_kernel<<<32, 256, 0, stream>>>(
            psum, psq, stats + 896 + l * 64, 2304, 2, (float)(2 * XYZ));
        xcur = A;
    }

    // ---- cls branch (GN of layer-1 output fused into conv staging) ----
    conv3x3_kernel<1><<<cgrid, cblk, 0, stream>>>(A, cwtB, stats + 960,
                                                  r_gn_g + 7 * 64, r_gn_b + 7 * 64,
                                                  hbuf, psum, psq);
    gn_stage2_kernel<<<32, 256, 0, stream>>>(psum, psq, stats, 576, 1, (float)XYZ);
    head_kernel<18><<<(XYZ + 255) / 256, 256, 0, stream>>>(hbuf, stats, cls_gn_g,
                                                           cls_gn_b, cls_W2, out_cls);
}